// Round 10
// baseline (605.054 us; speedup 1.0000x reference)
//
#include <hip/hip_runtime.h>

#define B_ 8
#define T_ 2048
#define C_ 768
#define H_ 3072
#define BT_ (B_ * T_)
#define BC_ (B_ * C_)
#define WSEG 128
#define NWSEG 16
#define LSEG 128
#define NLSEG 16
#define LWARM 96

typedef unsigned short u16;
typedef short bf16x8 __attribute__((ext_vector_type(8)));
typedef float f32x4 __attribute__((ext_vector_type(4)));

__device__ __forceinline__ float b2f(u16 u) {
    union { unsigned i; float f; } w; w.i = ((unsigned)u) << 16; return w.f;
}
__device__ __forceinline__ u16 f2b(float f) {
    union { float f; unsigned i; } w; w.f = f;
    return (u16)((w.i + 0x7fffu + ((w.i >> 16) & 1u)) >> 16);
}

typedef __attribute__((address_space(3))) unsigned int lds_u32;
typedef const __attribute__((address_space(1))) unsigned int glb_u32;
__device__ __forceinline__ void gld_lds16(const void* g, void* l) {
    __builtin_amdgcn_global_load_lds((glb_u32*)g, (lds_u32*)l, 16, 0, 0);
}

// ------------------------------------------------ LayerNorm + token-shift mix (f32 in, bf16 out)
template<int NOUT>
__global__ void lnmix(const float* __restrict__ x, const float* __restrict__ w,
                      const float* __restrict__ b,
                      const float* __restrict__ m1, const float* __restrict__ m2,
                      const float* __restrict__ m3,
                      u16* __restrict__ o1, u16* __restrict__ o2, u16* __restrict__ o3) {
    int row = blockIdx.x;
    int t = row % T_;
    const float* xr = x + (size_t)row * C_;
    const float* xp = xr - C_;
    int tid = threadIdx.x;
    float s = 0.f, s2 = 0.f, ps = 0.f, ps2 = 0.f;
    for (int i = tid; i < C_; i += 256) {
        float v = xr[i]; s += v; s2 += v * v;
        if (t > 0) { float u = xp[i]; ps += u; ps2 += u * u; }
    }
    for (int off = 32; off > 0; off >>= 1) {
        s += __shfl_down(s, off);  s2 += __shfl_down(s2, off);
        ps += __shfl_down(ps, off); ps2 += __shfl_down(ps2, off);
    }
    __shared__ float red[4][4];
    int wid = tid >> 6, lane = tid & 63;
    if (lane == 0) { red[wid][0] = s; red[wid][1] = s2; red[wid][2] = ps; red[wid][3] = ps2; }
    __syncthreads();
    if (tid == 0) {
        float a0 = 0, a1 = 0, a2 = 0, a3 = 0;
        for (int i = 0; i < 4; ++i) { a0 += red[i][0]; a1 += red[i][1]; a2 += red[i][2]; a3 += red[i][3]; }
        red[0][0] = a0; red[0][1] = a1; red[0][2] = a2; red[0][3] = a3;
    }
    __syncthreads();
    float mu = red[0][0] * (1.f / C_);
    float rs = rsqrtf(red[0][1] * (1.f / C_) - mu * mu + 1e-5f);
    float pmu = red[0][2] * (1.f / C_);
    float prs = rsqrtf(red[0][3] * (1.f / C_) - pmu * pmu + 1e-5f);
    size_t ob = (size_t)row * C_;
    for (int i = tid; i < C_; i += 256) {
        float wi = w[i], bi = b[i];
        float n = (xr[i] - mu) * rs * wi + bi;
        float np = (t > 0) ? (xp[i] - pmu) * prs * wi + bi : 0.f;
        o1[ob + i] = f2b(fmaf(m1[i], n - np, np));
        o2[ob + i] = f2b(fmaf(m2[i], n - np, np));
        if constexpr (NOUT == 3) o3[ob + i] = f2b(fmaf(m3[i], n - np, np));
    }
}

// ------------------------------------------------ batched transpose-cast f32[R][N] -> bf16[N][R]
struct TCJ { const float* s; u16* d; int R, Ncol, nbx, b0; };
struct TC7 { TCJ j[7]; };
__global__ void tcast_all(TC7 jobs) {
    __shared__ float t[32][33];
    int bid = blockIdx.x;
    int ji = 0;
#pragma unroll
    for (int k = 1; k < 7; ++k) if (bid >= jobs.j[k].b0) ji = k;
    TCJ jb = jobs.j[ji];
    int local = bid - jb.b0;
    int bx = local % jb.nbx, by = local / jb.nbx;
    int c0 = bx * 32, r0 = by * 32;
    int col = threadIdx.x & 31, rw = threadIdx.x >> 5;
#pragma unroll
    for (int i = 0; i < 4; ++i) {
        int r = rw + i * 8;
        t[r][col] = jb.s[(size_t)(r0 + r) * jb.Ncol + c0 + col];
    }
    __syncthreads();
#pragma unroll
    for (int i = 0; i < 4; ++i) {
        int r = rw + i * 8;
        jb.d[(size_t)(c0 + r) * jb.R + r0 + col] = f2b(t[col][r]);
    }
}

// ------------------------------------------------ GEMM core: 128x256 tile, 4 waves, wave-tile 64x128
// 3-stage LDS pipeline, m201 phase order: ds_read -> STAGE -> lgkm(0) -> MFMA -> vmcnt(N) -> barrier.
__device__ __forceinline__ void gemm_core(const u16* __restrict__ A,
                                          const u16* __restrict__ WT,
                                          int K, int m0, int n0,
                                          u16* As, u16* Bs, f32x4 acc[4][8]) {
    const int tid = threadIdx.x;
    const int lane = tid & 63, wid = tid >> 6;
    const int wr = wid >> 1, wc = wid & 1;
    const int r16 = lane & 15, g = lane >> 4;

    const int srow = tid >> 2;
    const int sslot = tid & 3;
    const int sx = (srow >> 1) & 3;            // invariant under srow += 64*j
    const u16* gA0 = A + (size_t)(m0 + srow) * K + ((sslot ^ sx) << 3);
    const u16* gA1 = gA0 + (size_t)64 * K;
    const u16* gB0 = WT + (size_t)(n0 + srow) * K + ((sslot ^ sx) << 3);
    const u16* gB1 = gB0 + (size_t)64 * K;
    const u16* gB2 = gB0 + (size_t)128 * K;
    const u16* gB3 = gB0 + (size_t)192 * K;
    u16* lA = As + tid * 8;
    u16* lB = Bs + tid * 8;

    int offA[4], offB[8];
#pragma unroll
    for (int m = 0; m < 4; ++m) {
        int row = wr * 64 + m * 16 + r16;
        offA[m] = row * 32 + (g ^ ((row >> 1) & 3)) * 8;
    }
#pragma unroll
    for (int n = 0; n < 8; ++n) {
        int rob = wc * 128 + n * 16 + r16;
        offB[n] = rob * 32 + (g ^ ((rob >> 1) & 3)) * 8;
    }

#define STAGE6(ao, bo) do { \
        gld_lds16(gA0, lA + (ao));        gld_lds16(gA1, lA + (ao) + 2048); \
        gld_lds16(gB0, lB + (bo));        gld_lds16(gB1, lB + (bo) + 2048); \
        gld_lds16(gB2, lB + (bo) + 4096); gld_lds16(gB3, lB + (bo) + 6144); \
        gA0 += 32; gA1 += 32; gB0 += 32; gB1 += 32; gB2 += 32; gB3 += 32; } while (0)

    const int nk = K >> 5;
    // prologue: stage K-tiles 0,1 into buffers 0,1; wait for tile 0
    STAGE6(0, 0);
    STAGE6(4096, 8192);
    asm volatile("s_waitcnt vmcnt(6)" ::: "memory");
    __builtin_amdgcn_s_barrier();
    int wA = 8192, wB = 16384;    // next write: buffer 2
    int rA = 0, rB = 0;

    for (int kt = 0; kt < nk; ++kt) {
        // 1. ds_read current tile into register fragments
        const u16* Ab = As + rA;
        const u16* Bb = Bs + rB;
        bf16x8 af[4], bg[8];
#pragma unroll
        for (int m = 0; m < 4; ++m) af[m] = *(const bf16x8*)(Ab + offA[m]);
#pragma unroll
        for (int n = 0; n < 8; ++n) bg[n] = *(const bf16x8*)(Bb + offB[n]);
        __builtin_amdgcn_sched_barrier(0);
        // 2. stage tile t+2 (WAR-safe: its last readers drained lgkm before prior barrier)
        if (kt + 2 < nk) {
            STAGE6(wA, wB);
            wA += 4096; if (wA == 12288) wA = 0;
            wB += 8192; if (wB == 24576) wB = 0;
        }
        // 3. wait fragments, then MFMA cluster under setprio
        asm volatile("s_waitcnt lgkmcnt(0)" ::: "memory");
        __builtin_amdgcn_sched_barrier(0);
        __builtin_amdgcn_s_setprio(1);
#pragma unroll
        for (int m = 0; m < 4; ++m)
#pragma unroll
            for (int n = 0; n < 8; ++n)
                acc[m][n] = __builtin_amdgcn_mfma_f32_16x16x32_bf16(af[m], bg[n], acc[m][n], 0, 0, 0);
        __builtin_amdgcn_s_setprio(0);
        __builtin_amdgcn_sched_barrier(0);
        // 4. counted vmcnt (next tile resident) + raw barrier
        if (kt + 1 < nk) {
            if (kt + 2 < nk) asm volatile("s_waitcnt vmcnt(6)" ::: "memory");
            else             asm volatile("s_waitcnt vmcnt(0)" ::: "memory");
            __builtin_amdgcn_sched_barrier(0);
            __builtin_amdgcn_s_barrier();
        }
        rA += 4096; if (rA == 12288) rA = 0;
        rB += 8192; if (rB == 24576) rB = 0;
    }
#undef STAGE6
}

// bijective XCD-chunked remap (m204), COLUMN-MAJOR within XCD:
// consecutive nids on one XCD share bx -> B weight panel stays L2-resident.
__device__ __forceinline__ void xcd_remap2(int& bx, int& by) {
    const int gx = gridDim.x, gy = gridDim.y;
    const int nwg = gx * gy;
    const int lin = blockIdx.y * gx + blockIdx.x;
    const int q = nwg >> 3, r = nwg & 7;
    const int xcd = lin & 7, pos = lin >> 3;
    const int nid = (xcd < r ? xcd * (q + 1) : r * (q + 1) + (xcd - r) * q) + pos;
    bx = nid / gy;        // B-panel index (stationary within XCD chunk)
    by = nid % gy;        // A streams
}

// ------------------------------------------------ single GEMM (bf16 out)
// MODE: 0 none, 1 sigmoid, 2 relu^2.  EMUL: multiply by bf16 gate Emul[row*N+col].
template<int MODE, bool EMUL>
__global__ __launch_bounds__(256, 2)
void gemm2(const u16* __restrict__ A, const u16* __restrict__ WT,
           u16* __restrict__ Cout, const u16* __restrict__ Emul, int N, int K) {
    __shared__ u16 As[12288];
    __shared__ u16 Bs[24576];
    int bx, by;
    xcd_remap2(bx, by);
    const int m0 = by << 7, n0 = bx << 8;
    f32x4 acc[4][8];
#pragma unroll
    for (int i = 0; i < 4; ++i)
#pragma unroll
        for (int j = 0; j < 8; ++j)
#pragma unroll
            for (int q = 0; q < 4; ++q) acc[i][j][q] = 0.f;
    gemm_core(A, WT, K, m0, n0, As, Bs, acc);

    const int lane = threadIdx.x & 63, wid = threadIdx.x >> 6;
    const int wr = wid >> 1, wc = wid & 1;
    const int r16 = lane & 15, g = lane >> 4;
#pragma unroll
    for (int m = 0; m < 4; ++m)
#pragma unroll
        for (int n = 0; n < 8; ++n)
#pragma unroll
            for (int j = 0; j < 4; ++j) {
                int row = m0 + wr * 64 + m * 16 + g * 4 + j;
                int col = n0 + wc * 128 + n * 16 + r16;
                float v = acc[m][n][j];
                if constexpr (MODE == 1) v = 1.f / (1.f + expf(-v));
                if constexpr (MODE == 2) { v = fmaxf(v, 0.f); v = v * v; }
                size_t o = (size_t)row * N + col;
                if constexpr (EMUL) v *= b2f(Emul[o]);
                Cout[o] = f2b(v);
            }
}

// ------------------------------------------------ fused K/V/R projections (blockIdx.z = slice)
struct P3 {
    const u16 *A0, *A1, *A2;
    const u16 *W0, *W1, *W2;
    u16 *O0, *O1, *O2;
};
__global__ __launch_bounds__(256, 2)
void proj3(P3 p, int N, int K) {
    __shared__ u16 As[12288];
    __shared__ u16 Bs[24576];
    const int z = blockIdx.z;
    const u16* A = (z == 0) ? p.A0 : (z == 1) ? p.A1 : p.A2;
    const u16* W = (z == 0) ? p.W0 : (z == 1) ? p.W1 : p.W2;
    u16* O = (z == 0) ? p.O0 : (z == 1) ? p.O1 : p.O2;
    int bx, by;
    xcd_remap2(bx, by);
    const int m0 = by << 7, n0 = bx << 8;
    f32x4 acc[4][8];
#pragma unroll
    for (int i = 0; i < 4; ++i)
#pragma unroll
        for (int j = 0; j < 8; ++j)
#pragma unroll
            for (int q = 0; q < 4; ++q) acc[i][j][q] = 0.f;
    gemm_core(A, W, K, m0, n0, As, Bs, acc);

    const int lane = threadIdx.x & 63, wid = threadIdx.x >> 6;
    const int wr = wid >> 1, wc = wid & 1;
    const int r16 = lane & 15, g = lane >> 4;
    const bool sig = (z == 2);
#pragma unroll
    for (int m = 0; m < 4; ++m)
#pragma unroll
        for (int n = 0; n < 8; ++n)
#pragma unroll
            for (int j = 0; j < 4; ++j) {
                int row = m0 + wr * 64 + m * 16 + g * 4 + j;
                int col = n0 + wc * 128 + n * 16 + r16;
                float v = acc[m][n][j];
                if (sig) v = 1.f / (1.f + expf(-v));
                O[(size_t)row * N + col] = f2b(v);
            }
}

// ------------------------------------------------ fused FFN1 (relu^2) + Rr (sigmoid) dispatch
struct J2 {
    const u16 *A0, *W0; u16 *O0;   // FFN1: N=3072
    const u16 *A1, *W1; u16 *O1;   // Rr:   N=768
};
__global__ __launch_bounds__(256, 2)
void ffn1rr(J2 p, int K) {
    __shared__ u16 As[12288];
    __shared__ u16 Bs[24576];
    int bx, by;
    xcd_remap2(bx, by);
    const bool isF = (bx < 12);
    const u16* A = isF ? p.A0 : p.A1;
    const u16* W = isF ? p.W0 : p.W1;
    u16* O = isF ? p.O0 : p.O1;
    const int N = isF ? 3072 : 768;
    const int m0 = by << 7;
    const int n0 = (isF ? bx : bx - 12) << 8;
    f32x4 acc[4][8];
#pragma unroll
    for (int i = 0; i < 4; ++i)
#pragma unroll
        for (int j = 0; j < 8; ++j)
#pragma unroll
            for (int q = 0; q < 4; ++q) acc[i][j][q] = 0.f;
    gemm_core(A, W, K, m0, n0, As, Bs, acc);

    const int lane = threadIdx.x & 63, wid = threadIdx.x >> 6;
    const int wr = wid >> 1, wc = wid & 1;
    const int r16 = lane & 15, g = lane >> 4;
#pragma unroll
    for (int m = 0; m < 4; ++m)
#pragma unroll
        for (int n = 0; n < 8; ++n)
#pragma unroll
            for (int j = 0; j < 4; ++j) {
                int row = m0 + wr * 64 + m * 16 + g * 4 + j;
                int col = n0 + wc * 128 + n * 16 + r16;
                float v = acc[m][n][j];
                if (isF) { v = fmaxf(v, 0.f); v = v * v; }
                else     { v = 1.f / (1.f + expf(-v)); }
                O[(size_t)row * N + col] = f2b(v);
            }
}

// ------------------------------------------------ WKV segmented scan
__global__ void wkv_p1(const float* __restrict__ td, const u16* __restrict__ K,
                       const u16* __restrict__ V, float* __restrict__ st) {
    int bc = blockIdx.x * 256 + threadIdx.x;
    int seg = blockIdx.y;
    int b = bc / C_, c = bc - b * C_;
    float w = -expf(td[c]);
    size_t off = (size_t)b * T_ * C_ + (size_t)seg * WSEG * C_ + c;
    float aa = 0.f, bb = 0.f, pp = -1e38f;
#pragma unroll 4
    for (int i = 0; i < WSEG; ++i) {
        float kt = b2f(K[off + (size_t)i * C_]);
        float vt = b2f(V[off + (size_t)i * C_]);
        float ww2 = pp + w;
        float p2 = fmaxf(ww2, kt);
        float e1 = expf(ww2 - p2);
        float e2 = expf(kt - p2);
        aa = e1 * aa + e2 * vt;
        bb = e1 * bb + e2;
        pp = p2;
    }
    int sidx = seg * 3 * BC_ + bc;
    st[sidx] = aa; st[sidx + BC_] = bb; st[sidx + 2 * BC_] = pp;
}

__global__ void wkv_p2(const float* __restrict__ td, const float* __restrict__ st,
                       float* __restrict__ ini) {
    int bc = blockIdx.x * 256 + threadIdx.x;
    int c = bc % C_;
    float wL = -expf(td[c]) * (float)WSEG;
    float aa = 0.f, bb = 0.f, pp = -1e38f;
    for (int s = 0; s < NWSEG; ++s) {
        int sidx = s * 3 * BC_ + bc;
        ini[sidx] = aa; ini[sidx + BC_] = bb; ini[sidx + 2 * BC_] = pp;
        float la = st[sidx], lb = st[sidx + BC_], lp = st[sidx + 2 * BC_];
        float ppw = pp + wL;
        float p = fmaxf(ppw, lp);
        float e1 = expf(ppw - p), e2 = expf(lp - p);
        aa = e1 * aa + e2 * la;
        bb = e1 * bb + e2 * lb;
        pp = p;
    }
}

// p3 applies the sigmoid(R) gate: writes RY = R * y
__global__ void wkv_p3(const float* __restrict__ td, const float* __restrict__ tf,
                       const u16* __restrict__ K, const u16* __restrict__ V,
                       const u16* __restrict__ R, const float* __restrict__ ini,
                       u16* __restrict__ RY) {
    int bc = blockIdx.x * 256 + threadIdx.x;
    int seg = blockIdx.y;
    int b = bc / C_, c = bc - b * C_;
    float w = -expf(td[c]);
    float u = tf[c];
    int sidx = seg * 3 * BC_ + bc;
    float aa = ini[sidx], bb = ini[sidx + BC_], pp = ini[sidx + 2 * BC_];
    size_t off = (size_t)b * T_ * C_ + (size_t)seg * WSEG * C_ + c;
#pragma unroll 4
    for (int i = 0; i < WSEG; ++i) {
        float kt = b2f(K[off + (size_t)i * C_]);
        float vt = b2f(V[off + (size_t)i * C_]);
        float rr = b2f(R[off + (size_t)i * C_]);
        float ww = u + kt;
        float p = fmaxf(pp, ww);
        float e1 = expf(pp - p);
        float e2 = expf(ww - p);
        RY[off + (size_t)i * C_] = f2b(rr * (e1 * aa + e2 * vt) / (e1 * bb + e2));
        float ww2 = pp + w;
        float p2 = fmaxf(ww2, kt);
        float e1b = expf(ww2 - p2);
        float e2b = expf(kt - p2);
        aa = e1b * aa + e2b * vt;
        bb = e1b * bb + e2b;
        pp = p2;
    }
}

// ------------------------------------------------ LIF + residual (bf16 input, segmented warm-up)
__global__ void lif_add_b(const u16* __restrict__ cur, const float* __restrict__ base,
                          float* __restrict__ out) {
    int bc = blockIdx.x * 256 + threadIdx.x;
    int seg = blockIdx.y;
    int b = bc / C_, c = bc - b * C_;
    size_t rowbase = (size_t)b * T_ * C_ + c;
    int t0 = seg * LSEG;
    int tw = t0 - LWARM; if (tw < 0) tw = 0;
    int nw = t0 - tw;
    float v = 0.f;
    const u16* cp = cur + rowbase + (size_t)tw * C_;
#pragma unroll 8
    for (int i = 0; i < nw; ++i) {
        float xt = b2f(cp[(size_t)i * C_]);
        v += (xt - v) * 0.5f;
        v = (v >= 1.f) ? 0.f : v;
    }
    const u16* c2 = cur + rowbase + (size_t)t0 * C_;
    const float* bp = base + rowbase + (size_t)t0 * C_;
    float* op = out + rowbase + (size_t)t0 * C_;
#pragma unroll 8
    for (int i = 0; i < LSEG; ++i) {
        float xt = b2f(c2[(size_t)i * C_]);
        v += (xt - v) * 0.5f;
        float sp = (v >= 1.f) ? 1.f : 0.f;
        op[(size_t)i * C_] = bp[(size_t)i * C_] + sp;
        v = (sp > 0.f) ? 0.f : v;
    }
}

// ------------------------------------------------ launcher
extern "C" void kernel_launch(void* const* d_in, const int* in_sizes, int n_in,
                              void* d_out, int out_size, void* d_ws, size_t ws_size,
                              hipStream_t stream) {
    const float* x    = (const float*)d_in[0];
    const float* ln1w = (const float*)d_in[1];
    const float* ln1b = (const float*)d_in[2];
    const float* ln2w = (const float*)d_in[3];
    const float* ln2b = (const float*)d_in[4];
    const float* td   = (const float*)d_in[5];
    const float* tf   = (const float*)d_in[6];
    const float* amk  = (const float*)d_in[7];
    const float* amv  = (const float*)d_in[8];
    const float* amr  = (const float*)d_in[9];
    const float* aWk  = (const float*)d_in[10];
    const float* aWv  = (const float*)d_in[11];
    const float* aWr  = (const float*)d_in[12];
    const float* aWo  = (const float*)d_in[13];
    const float* fmk  = (const float*)d_in[14];
    const float* fmr  = (const float*)d_in[15];
    const float* fWk  = (const float*)d_in[16];
    const float* fWv  = (const float*)d_in[17];
    const float* fWr  = (const float*)d_in[18];
    float* out = (float*)d_out;

    const size_t NBC = (size_t)BT_ * C_;
    u16* WkT = (u16*)d_ws;
    u16* WvT = WkT + 589824;
    u16* WrT = WvT + 589824;
    u16* WoT = WrT + 589824;
    u16* FrT = WoT + 589824;
    u16* FkT = FrT + 589824;                  // [3072][768]
    u16* FvT = FkT + 2359296;                 // [768][3072]
    float* st  = (float*)(FvT + 2359296);
    float* ini = st + NWSEG * 3 * BC_;
    u16* S0 = (u16*)(ini + NWSEG * 3 * BC_);
    u16* S1 = S0 + NBC;
    u16* S2 = S1 + NBC;
    u16* S3 = S2 + NBC;
    u16* Hbuf = S3 + NBC;
    size_t fixed_b = (size_t)((char*)Hbuf - (char*)d_ws);

    // FFN chunking (H bf16 chunk + F bf16 chunk after it)
    int NCH = 4;
    if (ws_size >= fixed_b + ((size_t)BT_ * H_ + NBC) * 2) NCH = 1;
    else if (ws_size >= fixed_b + ((size_t)(BT_ / 2) * H_ + NBC / 2) * 2) NCH = 2;
    const int CH = BT_ / NCH;
    u16* Fbuf = Hbuf + (size_t)CH * H_;

    u16* Kb = (u16*)d_out;
    u16* Vb = Kb + NBC;

    // 0. weights -> bf16 [N][K] (one batched dispatch)
    {
        TC7 jobs;
        const float* srcs[7] = {aWk, aWv, aWr, aWo, fWr, fWk, fWv};
        u16* dsts[7] = {WkT, WvT, WrT, WoT, FrT, FkT, FvT};
        int Rs[7]    = {768, 768, 768, 768, 768, 768, 3072};
        int Ns[7]    = {768, 768, 768, 768, 768, 3072, 768};
        int b0 = 0;
        for (int k = 0; k < 7; ++k) {
            jobs.j[k].s = srcs[k]; jobs.j[k].d = dsts[k];
            jobs.j[k].R = Rs[k]; jobs.j[k].Ncol = Ns[k];
            jobs.j[k].nbx = Ns[k] / 32; jobs.j[k].b0 = b0;
            b0 += (Ns[k] / 32) * (Rs[k] / 32);
        }
        tcast_all<<<b0, 256, 0, stream>>>(jobs);
    }

    // 1. xk,xv,xr = mix(ln1(x)) -> S0,S1,S2
    lnmix<3><<<BT_, 256, 0, stream>>>(x, ln1w, ln1b, amk, amv, amr, S0, S1, S2);
    // 2. K,V,sigmoid(R) in one fused dispatch
    {
        P3 p{S0, S1, S2, WkT, WvT, WrT, Kb, Vb, S3};
        proj3<<<dim3(3, 128, 3), 256, 0, stream>>>(p, C_, C_);
    }
    // 3. RY = sigmoid(R) * wkv(K,V) -> S0
    wkv_p1<<<dim3(BC_ / 256, NWSEG), 256, 0, stream>>>(td, Kb, Vb, st);
    wkv_p2<<<BC_ / 256, 256, 0, stream>>>(td, st, ini);
    wkv_p3<<<dim3(BC_ / 256, NWSEG), 256, 0, stream>>>(td, tf, Kb, Vb, S3, ini, S0);
    // 4. A_out = RY @ Wo -> bf16 S1
    gemm2<0, false><<<dim3(3, 128), 256, 0, stream>>>(S0, WoT, S1, nullptr, C_, C_);
    // 5. X2 = x + lif(A_out) -> d_out
    lif_add_b<<<dim3(BC_ / 256, NLSEG), 256, 0, stream>>>(S1, x, out);
    // 6. xk2 -> S0, xr2 -> S1
    lnmix<2><<<BT_, 256, 0, stream>>>(out, ln2w, ln2b, fmk, fmr, nullptr, S0, S1, nullptr);

    if (NCH == 1) {
        // 7. fused: H = relu^2(xk2 @ fWk), RR = sigmoid(xr2 @ fWr)
        J2 p{S0, FkT, Hbuf, S1, FrT, S2};
        ffn1rr<<<dim3(15, 128), 256, 0, stream>>>(p, C_);
        // 8. F = RR * (H @ fWv) -> Fbuf; out += lif(F)
        gemm2<0, true><<<dim3(3, 128), 256, 0, stream>>>(Hbuf, FvT, Fbuf, S2, C_, H_);
        lif_add_b<<<dim3(BC_ / 256, NLSEG), 256, 0, stream>>>(Fbuf, out, out);
    } else {
        // 7. RR = sigmoid(xr2 @ fWr) -> S2
        gemm2<1, false><<<dim3(3, 128), 256, 0, stream>>>(S1, FrT, S2, nullptr, C_, C_);
        // 8. FFN per chunk
        for (int ch = 0; ch < NCH; ++ch) {
            const u16* xk2c = S0 + (size_t)ch * CH * C_;
            const u16* rrc  = S2 + (size_t)ch * CH * C_;
            gemm2<2, false><<<dim3(12, CH / 128), 256, 0, stream>>>(xk2c, FkT, Hbuf, nullptr, H_, C_);
            gemm2<0, true><<<dim3(3, CH / 128), 256, 0, stream>>>(Hbuf, FvT, Fbuf, rrc, C_, H_);
            lif_add_b<<<dim3((CH / T_) * C_ / 256, NLSEG), 256, 0, stream>>>(
                Fbuf, out + (size_t)ch * CH * C_, out + (size_t)ch * CH * C_);
        }
    }
}

// Round 11
// 597.258 us; speedup vs baseline: 1.0131x; 1.0131x over previous
//
#include <hip/hip_runtime.h>

#define B_ 8
#define T_ 2048
#define C_ 768
#define H_ 3072
#define BT_ (B_ * T_)
#define BC_ (B_ * C_)
#define WSEG 128
#define NWSEG 16
#define LSEG 128
#define NLSEG 16
#define LWARM 96

typedef unsigned short u16;
typedef short bf16x8 __attribute__((ext_vector_type(8)));
typedef float f32x4 __attribute__((ext_vector_type(4)));

__device__ __forceinline__ float b2f(u16 u) {
    union { unsigned i; float f; } w; w.i = ((unsigned)u) << 16; return w.f;
}
__device__ __forceinline__ u16 f2b(float f) {
    union { float f; unsigned i; } w; w.f = f;
    return (u16)((w.i + 0x7fffu + ((w.i >> 16) & 1u)) >> 16);
}

typedef __attribute__((address_space(3))) unsigned int lds_u32;
typedef const __attribute__((address_space(1))) unsigned int glb_u32;
__device__ __forceinline__ void gld_lds16(const void* g, void* l) {
    __builtin_amdgcn_global_load_lds((glb_u32*)g, (lds_u32*)l, 16, 0, 0);
}

// ------------------------------------------------ LayerNorm + token-shift mix (f32 in, bf16 out)
template<int NOUT>
__global__ void lnmix(const float* __restrict__ x, const float* __restrict__ w,
                      const float* __restrict__ b,
                      const float* __restrict__ m1, const float* __restrict__ m2,
                      const float* __restrict__ m3,
                      u16* __restrict__ o1, u16* __restrict__ o2, u16* __restrict__ o3) {
    int row = blockIdx.x;
    int t = row % T_;
    const float* xr = x + (size_t)row * C_;
    const float* xp = xr - C_;
    int tid = threadIdx.x;
    float s = 0.f, s2 = 0.f, ps = 0.f, ps2 = 0.f;
    for (int i = tid; i < C_; i += 256) {
        float v = xr[i]; s += v; s2 += v * v;
        if (t > 0) { float u = xp[i]; ps += u; ps2 += u * u; }
    }
    for (int off = 32; off > 0; off >>= 1) {
        s += __shfl_down(s, off);  s2 += __shfl_down(s2, off);
        ps += __shfl_down(ps, off); ps2 += __shfl_down(ps2, off);
    }
    __shared__ float red[4][4];
    int wid = tid >> 6, lane = tid & 63;
    if (lane == 0) { red[wid][0] = s; red[wid][1] = s2; red[wid][2] = ps; red[wid][3] = ps2; }
    __syncthreads();
    if (tid == 0) {
        float a0 = 0, a1 = 0, a2 = 0, a3 = 0;
        for (int i = 0; i < 4; ++i) { a0 += red[i][0]; a1 += red[i][1]; a2 += red[i][2]; a3 += red[i][3]; }
        red[0][0] = a0; red[0][1] = a1; red[0][2] = a2; red[0][3] = a3;
    }
    __syncthreads();
    float mu = red[0][0] * (1.f / C_);
    float rs = rsqrtf(red[0][1] * (1.f / C_) - mu * mu + 1e-5f);
    float pmu = red[0][2] * (1.f / C_);
    float prs = rsqrtf(red[0][3] * (1.f / C_) - pmu * pmu + 1e-5f);
    size_t ob = (size_t)row * C_;
    for (int i = tid; i < C_; i += 256) {
        float wi = w[i], bi = b[i];
        float n = (xr[i] - mu) * rs * wi + bi;
        float np = (t > 0) ? (xp[i] - pmu) * prs * wi + bi : 0.f;
        o1[ob + i] = f2b(fmaf(m1[i], n - np, np));
        o2[ob + i] = f2b(fmaf(m2[i], n - np, np));
        if constexpr (NOUT == 3) o3[ob + i] = f2b(fmaf(m3[i], n - np, np));
    }
}

// ------------------------------------------------ batched transpose-cast f32[R][N] -> bf16[N][R]
struct TCJ { const float* s; u16* d; int R, Ncol, nbx, b0; };
struct TC7 { TCJ j[7]; };
__global__ void tcast_all(TC7 jobs) {
    __shared__ float t[32][33];
    int bid = blockIdx.x;
    int ji = 0;
#pragma unroll
    for (int k = 1; k < 7; ++k) if (bid >= jobs.j[k].b0) ji = k;
    TCJ jb = jobs.j[ji];
    int local = bid - jb.b0;
    int bx = local % jb.nbx, by = local / jb.nbx;
    int c0 = bx * 32, r0 = by * 32;
    int col = threadIdx.x & 31, rw = threadIdx.x >> 5;
#pragma unroll
    for (int i = 0; i < 4; ++i) {
        int r = rw + i * 8;
        t[r][col] = jb.s[(size_t)(r0 + r) * jb.Ncol + c0 + col];
    }
    __syncthreads();
#pragma unroll
    for (int i = 0; i < 4; ++i) {
        int r = rw + i * 8;
        jb.d[(size_t)(c0 + r) * jb.R + r0 + col] = f2b(t[col][r]);
    }
}

// ------------------------------------------------ 256x256 GEMM core: 8 waves (2Mx4N), BK=32,
// tri-buffered LDS, 2 phases/K-tile, counted vmcnt (T4), setprio around MFMA (T5).
// L: 3 x 16384 u16 (per buffer: A 8192 u16, B 8192 u16).
__device__ __forceinline__ void gemm_core256(const u16* __restrict__ A,
                                             const u16* __restrict__ WT,
                                             int K, int m0, int n0,
                                             u16* L, f32x4 acc[8][4]) {
    const int tid = threadIdx.x;
    const int lane = tid & 63, wid = tid >> 6;
    const int wr = wid >> 2, wc = wid & 3;      // 2M x 4N
    const int r16 = lane & 15, g = lane >> 4;

    const int srow = tid >> 2;                  // 0..127 (+128 for second half)
    const int sunit = tid & 3;
    const int sx = (srow >> 1) & 3;             // invariant under srow += 128
    const u16* gA0 = A + (size_t)(m0 + srow) * K + ((sunit ^ sx) << 3);
    const u16* gA1 = gA0 + (size_t)128 * K;
    const u16* gB0 = WT + (size_t)(n0 + srow) * K + ((sunit ^ sx) << 3);
    const u16* gB1 = gB0 + (size_t)128 * K;
    u16* lA0 = L + tid * 8;
    u16* lA1 = L + 4096 + tid * 8;
    u16* lB0 = L + 8192 + tid * 8;
    u16* lB1 = L + 12288 + tid * 8;

    int offA[8], offB[4];
#pragma unroll
    for (int m = 0; m < 8; ++m) {
        int row = wr * 128 + m * 16 + r16;
        offA[m] = row * 32 + (g ^ ((row >> 1) & 3)) * 8;
    }
#pragma unroll
    for (int n = 0; n < 4; ++n) {
        int rob = wc * 64 + n * 16 + r16;
        offB[n] = 8192 + rob * 32 + (g ^ ((rob >> 1) & 3)) * 8;
    }

#define STGA(buf) do { \
        gld_lds16(gA0, lA0 + (buf) * 16384); gld_lds16(gA1, lA1 + (buf) * 16384); \
        gA0 += 32; gA1 += 32; } while (0)
#define STGB(buf) do { \
        gld_lds16(gB0, lB0 + (buf) * 16384); gld_lds16(gB1, lB1 + (buf) * 16384); \
        gB0 += 32; gB1 += 32; } while (0)

    const int nt = K >> 5;
    // prologue: stage tiles 0,1; wait tile 0 resident
    STGA(0); STGB(0);
    STGA(1); STGB(1);
    asm volatile("s_waitcnt vmcnt(4)" ::: "memory");
    __builtin_amdgcn_sched_barrier(0);
    __builtin_amdgcn_s_barrier();

    int rb = 0, wb = 2;
    for (int t = 0; t < nt; ++t) {
        const u16* Lb = L + rb * 16384;
        const bool stg = (t + 2 < nt);
        // ---- phase A: frags m0..3 + all B, stage A-half of t+2
        bf16x8 a0[4], bg[4];
#pragma unroll
        for (int m = 0; m < 4; ++m) a0[m] = *(const bf16x8*)(Lb + offA[m]);
#pragma unroll
        for (int n = 0; n < 4; ++n) bg[n] = *(const bf16x8*)(Lb + offB[n]);
        __builtin_amdgcn_sched_barrier(0);
        if (stg) STGA(wb);
        __builtin_amdgcn_s_barrier();
        asm volatile("s_waitcnt lgkmcnt(0)" ::: "memory");
        __builtin_amdgcn_sched_barrier(0);
        __builtin_amdgcn_s_setprio(1);
#pragma unroll
        for (int m = 0; m < 4; ++m)
#pragma unroll
            for (int n = 0; n < 4; ++n)
                acc[m][n] = __builtin_amdgcn_mfma_f32_16x16x32_bf16(a0[m], bg[n], acc[m][n], 0, 0, 0);
        __builtin_amdgcn_s_setprio(0);
        __builtin_amdgcn_sched_barrier(0);
        __builtin_amdgcn_s_barrier();
        // ---- phase B: frags m4..7, stage B-half of t+2
        bf16x8 a1[4];
#pragma unroll
        for (int m = 0; m < 4; ++m) a1[m] = *(const bf16x8*)(Lb + offA[4 + m]);
        __builtin_amdgcn_sched_barrier(0);
        if (stg) STGB(wb);
        __builtin_amdgcn_s_barrier();
        asm volatile("s_waitcnt lgkmcnt(0)" ::: "memory");
        __builtin_amdgcn_sched_barrier(0);
        __builtin_amdgcn_s_setprio(1);
#pragma unroll
        for (int m = 0; m < 4; ++m)
#pragma unroll
            for (int n = 0; n < 4; ++n)
                acc[4 + m][n] = __builtin_amdgcn_mfma_f32_16x16x32_bf16(a1[m], bg[n], acc[4 + m][n], 0, 0, 0);
        __builtin_amdgcn_s_setprio(0);
        __builtin_amdgcn_sched_barrier(0);
        // ---- tile boundary: counted vmcnt (never 0 until tail) + barrier
        if (t + 1 < nt) {
            if (stg) asm volatile("s_waitcnt vmcnt(4)" ::: "memory");
            else     asm volatile("s_waitcnt vmcnt(0)" ::: "memory");
            __builtin_amdgcn_sched_barrier(0);
            __builtin_amdgcn_s_barrier();
        }
        rb = (rb == 2) ? 0 : rb + 1;
        wb = (wb == 2) ? 0 : wb + 1;
    }
#undef STGA
#undef STGB
}

// bijective XCD-chunked remap (m204), row-major within XCD (A-panel L2-resident)
__device__ __forceinline__ void xcd_remap2(int& bx, int& by) {
    const int gx = gridDim.x;
    const int nwg = gx * gridDim.y;
    const int lin = blockIdx.y * gx + blockIdx.x;
    const int q = nwg >> 3, r = nwg & 7;
    const int xcd = lin & 7, pos = lin >> 3;
    const int nid = (xcd < r ? xcd * (q + 1) : r * (q + 1) + (xcd - r) * q) + pos;
    bx = nid % gx;
    by = nid / gx;
}

__device__ __forceinline__ void epilogue256(f32x4 acc[8][4], u16* O, const u16* Emul,
                                            int m0, int n0, int N, int mode, bool emul) {
    const int lane = threadIdx.x & 63, wid = threadIdx.x >> 6;
    const int wr = wid >> 2, wc = wid & 3;
    const int r16 = lane & 15, g = lane >> 4;
#pragma unroll
    for (int m = 0; m < 8; ++m)
#pragma unroll
        for (int n = 0; n < 4; ++n)
#pragma unroll
            for (int j = 0; j < 4; ++j) {
                int row = m0 + wr * 128 + m * 16 + g * 4 + j;
                int col = n0 + wc * 64 + n * 16 + r16;
                float v = acc[m][n][j];
                if (mode == 1) v = 1.f / (1.f + expf(-v));
                else if (mode == 2) { v = fmaxf(v, 0.f); v = v * v; }
                size_t o = (size_t)row * N + col;
                if (emul) v *= b2f(Emul[o]);
                O[o] = f2b(v);
            }
}

// ------------------------------------------------ single GEMM (bf16 out), 256x256 tile
template<int MODE, bool EMUL>
__global__ __launch_bounds__(512, 1)
void gemm256(const u16* __restrict__ A, const u16* __restrict__ WT,
             u16* __restrict__ Cout, const u16* __restrict__ Emul, int N, int K) {
    __shared__ u16 L[49152];
    int bx, by;
    xcd_remap2(bx, by);
    const int m0 = by << 8, n0 = bx << 8;
    f32x4 acc[8][4];
#pragma unroll
    for (int i = 0; i < 8; ++i)
#pragma unroll
        for (int j = 0; j < 4; ++j)
#pragma unroll
            for (int q = 0; q < 4; ++q) acc[i][j][q] = 0.f;
    gemm_core256(A, WT, K, m0, n0, L, acc);
    epilogue256(acc, Cout, Emul, m0, n0, N, MODE, EMUL);
}

// ------------------------------------------------ fused K/V/R projections (blockIdx.z = slice)
struct P3 {
    const u16 *A0, *A1, *A2;
    const u16 *W0, *W1, *W2;
    u16 *O0, *O1, *O2;
};
__global__ __launch_bounds__(512, 1)
void proj3(P3 p, int N, int K) {
    __shared__ u16 L[49152];
    const int z = blockIdx.z;
    const u16* A = (z == 0) ? p.A0 : (z == 1) ? p.A1 : p.A2;
    const u16* W = (z == 0) ? p.W0 : (z == 1) ? p.W1 : p.W2;
    u16* O = (z == 0) ? p.O0 : (z == 1) ? p.O1 : p.O2;
    int bx, by;
    xcd_remap2(bx, by);
    const int m0 = by << 8, n0 = bx << 8;
    f32x4 acc[8][4];
#pragma unroll
    for (int i = 0; i < 8; ++i)
#pragma unroll
        for (int j = 0; j < 4; ++j)
#pragma unroll
            for (int q = 0; q < 4; ++q) acc[i][j][q] = 0.f;
    gemm_core256(A, W, K, m0, n0, L, acc);
    epilogue256(acc, O, nullptr, m0, n0, N, (z == 2) ? 1 : 0, false);
}

// ------------------------------------------------ fused FFN1 (relu^2) + Rr (sigmoid)
struct J2 {
    const u16 *A0, *W0; u16 *O0;   // FFN1: N=3072
    const u16 *A1, *W1; u16 *O1;   // Rr:   N=768
};
__global__ __launch_bounds__(512, 1)
void ffn1rr(J2 p, int K) {
    __shared__ u16 L[49152];
    int bx, by;
    xcd_remap2(bx, by);
    const bool isF = (bx < 12);
    const u16* A = isF ? p.A0 : p.A1;
    const u16* W = isF ? p.W0 : p.W1;
    u16* O = isF ? p.O0 : p.O1;
    const int N = isF ? 3072 : 768;
    const int m0 = by << 8;
    const int n0 = (isF ? bx : bx - 12) << 8;
    f32x4 acc[8][4];
#pragma unroll
    for (int i = 0; i < 8; ++i)
#pragma unroll
        for (int j = 0; j < 4; ++j)
#pragma unroll
            for (int q = 0; q < 4; ++q) acc[i][j][q] = 0.f;
    gemm_core256(A, W, K, m0, n0, L, acc);
    epilogue256(acc, O, nullptr, m0, n0, N, isF ? 2 : 1, false);
}

// ------------------------------------------------ WKV segmented scan
__global__ void wkv_p1(const float* __restrict__ td, const u16* __restrict__ K,
                       const u16* __restrict__ V, float* __restrict__ st) {
    int bc = blockIdx.x * 256 + threadIdx.x;
    int seg = blockIdx.y;
    int b = bc / C_, c = bc - b * C_;
    float w = -expf(td[c]);
    size_t off = (size_t)b * T_ * C_ + (size_t)seg * WSEG * C_ + c;
    float aa = 0.f, bb = 0.f, pp = -1e38f;
#pragma unroll 4
    for (int i = 0; i < WSEG; ++i) {
        float kt = b2f(K[off + (size_t)i * C_]);
        float vt = b2f(V[off + (size_t)i * C_]);
        float ww2 = pp + w;
        float p2 = fmaxf(ww2, kt);
        float e1 = expf(ww2 - p2);
        float e2 = expf(kt - p2);
        aa = e1 * aa + e2 * vt;
        bb = e1 * bb + e2;
        pp = p2;
    }
    int sidx = seg * 3 * BC_ + bc;
    st[sidx] = aa; st[sidx + BC_] = bb; st[sidx + 2 * BC_] = pp;
}

__global__ void wkv_p2(const float* __restrict__ td, const float* __restrict__ st,
                       float* __restrict__ ini) {
    int bc = blockIdx.x * 256 + threadIdx.x;
    int c = bc % C_;
    float wL = -expf(td[c]) * (float)WSEG;
    float aa = 0.f, bb = 0.f, pp = -1e38f;
    for (int s = 0; s < NWSEG; ++s) {
        int sidx = s * 3 * BC_ + bc;
        ini[sidx] = aa; ini[sidx + BC_] = bb; ini[sidx + 2 * BC_] = pp;
        float la = st[sidx], lb = st[sidx + BC_], lp = st[sidx + 2 * BC_];
        float ppw = pp + wL;
        float p = fmaxf(ppw, lp);
        float e1 = expf(ppw - p), e2 = expf(lp - p);
        aa = e1 * aa + e2 * la;
        bb = e1 * bb + e2 * lb;
        pp = p;
    }
}

// p3 applies the sigmoid(R) gate: writes RY = R * y
__global__ void wkv_p3(const float* __restrict__ td, const float* __restrict__ tf,
                       const u16* __restrict__ K, const u16* __restrict__ V,
                       const u16* __restrict__ R, const float* __restrict__ ini,
                       u16* __restrict__ RY) {
    int bc = blockIdx.x * 256 + threadIdx.x;
    int seg = blockIdx.y;
    int b = bc / C_, c = bc - b * C_;
    float w = -expf(td[c]);
    float u = tf[c];
    int sidx = seg * 3 * BC_ + bc;
    float aa = ini[sidx], bb = ini[sidx + BC_], pp = ini[sidx + 2 * BC_];
    size_t off = (size_t)b * T_ * C_ + (size_t)seg * WSEG * C_ + c;
#pragma unroll 4
    for (int i = 0; i < WSEG; ++i) {
        float kt = b2f(K[off + (size_t)i * C_]);
        float vt = b2f(V[off + (size_t)i * C_]);
        float rr = b2f(R[off + (size_t)i * C_]);
        float ww = u + kt;
        float p = fmaxf(pp, ww);
        float e1 = expf(pp - p);
        float e2 = expf(ww - p);
        RY[off + (size_t)i * C_] = f2b(rr * (e1 * aa + e2 * vt) / (e1 * bb + e2));
        float ww2 = pp + w;
        float p2 = fmaxf(ww2, kt);
        float e1b = expf(ww2 - p2);
        float e2b = expf(kt - p2);
        aa = e1b * aa + e2b * vt;
        bb = e1b * bb + e2b;
        pp = p2;
    }
}

// ------------------------------------------------ LIF + residual (bf16 input, segmented warm-up)
__global__ void lif_add_b(const u16* __restrict__ cur, const float* __restrict__ base,
                          float* __restrict__ out) {
    int bc = blockIdx.x * 256 + threadIdx.x;
    int seg = blockIdx.y;
    int b = bc / C_, c = bc - b * C_;
    size_t rowbase = (size_t)b * T_ * C_ + c;
    int t0 = seg * LSEG;
    int tw = t0 - LWARM; if (tw < 0) tw = 0;
    int nw = t0 - tw;
    float v = 0.f;
    const u16* cp = cur + rowbase + (size_t)tw * C_;
#pragma unroll 8
    for (int i = 0; i < nw; ++i) {
        float xt = b2f(cp[(size_t)i * C_]);
        v += (xt - v) * 0.5f;
        v = (v >= 1.f) ? 0.f : v;
    }
    const u16* c2 = cur + rowbase + (size_t)t0 * C_;
    const float* bp = base + rowbase + (size_t)t0 * C_;
    float* op = out + rowbase + (size_t)t0 * C_;
#pragma unroll 8
    for (int i = 0; i < LSEG; ++i) {
        float xt = b2f(c2[(size_t)i * C_]);
        v += (xt - v) * 0.5f;
        float sp = (v >= 1.f) ? 1.f : 0.f;
        op[(size_t)i * C_] = bp[(size_t)i * C_] + sp;
        v = (sp > 0.f) ? 0.f : v;
    }
}

// ------------------------------------------------ launcher
extern "C" void kernel_launch(void* const* d_in, const int* in_sizes, int n_in,
                              void* d_out, int out_size, void* d_ws, size_t ws_size,
                              hipStream_t stream) {
    const float* x    = (const float*)d_in[0];
    const float* ln1w = (const float*)d_in[1];
    const float* ln1b = (const float*)d_in[2];
    const float* ln2w = (const float*)d_in[3];
    const float* ln2b = (const float*)d_in[4];
    const float* td   = (const float*)d_in[5];
    const float* tf   = (const float*)d_in[6];
    const float* amk  = (const float*)d_in[7];
    const float* amv  = (const float*)d_in[8];
    const float* amr  = (const float*)d_in[9];
    const float* aWk  = (const float*)d_in[10];
    const float* aWv  = (const float*)d_in[11];
    const float* aWr  = (const float*)d_in[12];
    const float* aWo  = (const float*)d_in[13];
    const float* fmk  = (const float*)d_in[14];
    const float* fmr  = (const float*)d_in[15];
    const float* fWk  = (const float*)d_in[16];
    const float* fWv  = (const float*)d_in[17];
    const float* fWr  = (const float*)d_in[18];
    float* out = (float*)d_out;

    const size_t NBC = (size_t)BT_ * C_;
    u16* WkT = (u16*)d_ws;
    u16* WvT = WkT + 589824;
    u16* WrT = WvT + 589824;
    u16* WoT = WrT + 589824;
    u16* FrT = WoT + 589824;
    u16* FkT = FrT + 589824;                  // [3072][768]
    u16* FvT = FkT + 2359296;                 // [768][3072]
    float* st  = (float*)(FvT + 2359296);
    float* ini = st + NWSEG * 3 * BC_;
    u16* S0 = (u16*)(ini + NWSEG * 3 * BC_);
    u16* S1 = S0 + NBC;
    u16* S2 = S1 + NBC;
    u16* S3 = S2 + NBC;
    u16* Hbuf = S3 + NBC;
    size_t fixed_b = (size_t)((char*)Hbuf - (char*)d_ws);

    // FFN chunking (H bf16 chunk + F bf16 chunk after it)
    int NCH = 4;
    if (ws_size >= fixed_b + ((size_t)BT_ * H_ + NBC) * 2) NCH = 1;
    else if (ws_size >= fixed_b + ((size_t)(BT_ / 2) * H_ + NBC / 2) * 2) NCH = 2;
    const int CH = BT_ / NCH;
    u16* Fbuf = Hbuf + (size_t)CH * H_;

    u16* Kb = (u16*)d_out;
    u16* Vb = Kb + NBC;

    // 0. weights -> bf16 [N][K] (one batched dispatch)
    {
        TC7 jobs;
        const float* srcs[7] = {aWk, aWv, aWr, aWo, fWr, fWk, fWv};
        u16* dsts[7] = {WkT, WvT, WrT, WoT, FrT, FkT, FvT};
        int Rs[7]    = {768, 768, 768, 768, 768, 768, 3072};
        int Ns[7]    = {768, 768, 768, 768, 768, 3072, 768};
        int b0 = 0;
        for (int k = 0; k < 7; ++k) {
            jobs.j[k].s = srcs[k]; jobs.j[k].d = dsts[k];
            jobs.j[k].R = Rs[k]; jobs.j[k].Ncol = Ns[k];
            jobs.j[k].nbx = Ns[k] / 32; jobs.j[k].b0 = b0;
            b0 += (Ns[k] / 32) * (Rs[k] / 32);
        }
        tcast_all<<<b0, 256, 0, stream>>>(jobs);
    }

    // 1. xk,xv,xr = mix(ln1(x)) -> S0,S1,S2
    lnmix<3><<<BT_, 256, 0, stream>>>(x, ln1w, ln1b, amk, amv, amr, S0, S1, S2);
    // 2. K,V,sigmoid(R) in one fused dispatch (256^2 tiles)
    {
        P3 p{S0, S1, S2, WkT, WvT, WrT, Kb, Vb, S3};
        proj3<<<dim3(3, 64, 3), 512, 0, stream>>>(p, C_, C_);
    }
    // 3. RY = sigmoid(R) * wkv(K,V) -> S0
    wkv_p1<<<dim3(BC_ / 256, NWSEG), 256, 0, stream>>>(td, Kb, Vb, st);
    wkv_p2<<<BC_ / 256, 256, 0, stream>>>(td, st, ini);
    wkv_p3<<<dim3(BC_ / 256, NWSEG), 256, 0, stream>>>(td, tf, Kb, Vb, S3, ini, S0);
    // 4. A_out = RY @ Wo -> bf16 S1
    gemm256<0, false><<<dim3(3, 64), 512, 0, stream>>>(S0, WoT, S1, nullptr, C_, C_);
    // 5. X2 = x + lif(A_out) -> d_out
    lif_add_b<<<dim3(BC_ / 256, NLSEG), 256, 0, stream>>>(S1, x, out);
    // 6. xk2 -> S0, xr2 -> S1
    lnmix<2><<<BT_, 256, 0, stream>>>(out, ln2w, ln2b, fmk, fmr, nullptr, S0, S1, nullptr);

    if (NCH == 1) {
        // 7. fused: H = relu^2(xk2 @ fWk), RR = sigmoid(xr2 @ fWr)
        J2 p{S0, FkT, Hbuf, S1, FrT, S2};
        ffn1rr<<<dim3(15, 64), 512, 0, stream>>>(p, C_);
        // 8. F = RR * (H @ fWv) -> Fbuf; out += lif(F)
        gemm256<0, true><<<dim3(3, 64), 512, 0, stream>>>(Hbuf, FvT, Fbuf, S2, C_, H_);
        lif_add_b<<<dim3(BC_ / 256, NLSEG), 256, 0, stream>>>(Fbuf, out, out);
    } else {
        // 7. RR = sigmoid(xr2 @ fWr) -> S2
        gemm256<1, false><<<dim3(3, 64), 512, 0, stream>>>(S1, FrT, S2, nullptr, C_, C_);
        // 8. FFN per chunk
        for (int ch = 0; ch < NCH; ++ch) {
            const u16* xk2c = S0 + (size_t)ch * CH * C_;
            const u16* rrc  = S2 + (size_t)ch * CH * C_;
            gemm256<2, false><<<dim3(12, CH / 256), 512, 0, stream>>>(xk2c, FkT, Hbuf, nullptr, H_, C_);
            gemm256<0, true><<<dim3(3, CH / 256), 512, 0, stream>>>(Hbuf, FvT, Fbuf, rrc, C_, H_);
            lif_add_b<<<dim3((CH / T_) * C_ / 256, NLSEG), 256, 0, stream>>>(
                Fbuf, out + (size_t)ch * CH * C_, out + (size_t)ch * CH * C_);
        }
    }
}

// Round 12
// 571.056 us; speedup vs baseline: 1.0595x; 1.0459x over previous
//
#include <hip/hip_runtime.h>

#define B_ 8
#define T_ 2048
#define C_ 768
#define H_ 3072
#define BT_ (B_ * T_)
#define BC_ (B_ * C_)
#define WSEG 128
#define NWSEG 16
#define LSEG 128
#define NLSEG 16
#define LWARM 96

typedef unsigned short u16;
typedef short bf16x8 __attribute__((ext_vector_type(8)));
typedef float f32x4 __attribute__((ext_vector_type(4)));

__device__ __forceinline__ float b2f(u16 u) {
    union { unsigned i; float f; } w; w.i = ((unsigned)u) << 16; return w.f;
}
__device__ __forceinline__ u16 f2b(float f) {
    union { float f; unsigned i; } w; w.f = f;
    return (u16)((w.i + 0x7fffu + ((w.i >> 16) & 1u)) >> 16);
}

typedef __attribute__((address_space(3))) unsigned int lds_u32;
typedef const __attribute__((address_space(1))) unsigned int glb_u32;
__device__ __forceinline__ void gld_lds16(const void* g, void* l) {
    __builtin_amdgcn_global_load_lds((glb_u32*)g, (lds_u32*)l, 16, 0, 0);
}

// ------------------------------------------------ LayerNorm + token-shift mix (f32 in, bf16 out)
template<int NOUT>
__global__ void lnmix(const float* __restrict__ x, const float* __restrict__ w,
                      const float* __restrict__ b,
                      const float* __restrict__ m1, const float* __restrict__ m2,
                      const float* __restrict__ m3,
                      u16* __restrict__ o1, u16* __restrict__ o2, u16* __restrict__ o3) {
    int row = blockIdx.x;
    int t = row % T_;
    const float* xr = x + (size_t)row * C_;
    const float* xp = xr - C_;
    int tid = threadIdx.x;
    float s = 0.f, s2 = 0.f, ps = 0.f, ps2 = 0.f;
    for (int i = tid; i < C_; i += 256) {
        float v = xr[i]; s += v; s2 += v * v;
        if (t > 0) { float u = xp[i]; ps += u; ps2 += u * u; }
    }
    for (int off = 32; off > 0; off >>= 1) {
        s += __shfl_down(s, off);  s2 += __shfl_down(s2, off);
        ps += __shfl_down(ps, off); ps2 += __shfl_down(ps2, off);
    }
    __shared__ float red[4][4];
    int wid = tid >> 6, lane = tid & 63;
    if (lane == 0) { red[wid][0] = s; red[wid][1] = s2; red[wid][2] = ps; red[wid][3] = ps2; }
    __syncthreads();
    if (tid == 0) {
        float a0 = 0, a1 = 0, a2 = 0, a3 = 0;
        for (int i = 0; i < 4; ++i) { a0 += red[i][0]; a1 += red[i][1]; a2 += red[i][2]; a3 += red[i][3]; }
        red[0][0] = a0; red[0][1] = a1; red[0][2] = a2; red[0][3] = a3;
    }
    __syncthreads();
    float mu = red[0][0] * (1.f / C_);
    float rs = rsqrtf(red[0][1] * (1.f / C_) - mu * mu + 1e-5f);
    float pmu = red[0][2] * (1.f / C_);
    float prs = rsqrtf(red[0][3] * (1.f / C_) - pmu * pmu + 1e-5f);
    size_t ob = (size_t)row * C_;
    for (int i = tid; i < C_; i += 256) {
        float wi = w[i], bi = b[i];
        float n = (xr[i] - mu) * rs * wi + bi;
        float np = (t > 0) ? (xp[i] - pmu) * prs * wi + bi : 0.f;
        o1[ob + i] = f2b(fmaf(m1[i], n - np, np));
        o2[ob + i] = f2b(fmaf(m2[i], n - np, np));
        if constexpr (NOUT == 3) o3[ob + i] = f2b(fmaf(m3[i], n - np, np));
    }
}

// ------------------------------------------------ batched transpose-cast f32[R][N] -> bf16[N][R]
struct TCJ { const float* s; u16* d; int R, Ncol, nbx, b0; };
struct TC7 { TCJ j[7]; };
__global__ void tcast_all(TC7 jobs) {
    __shared__ float t[32][33];
    int bid = blockIdx.x;
    int ji = 0;
#pragma unroll
    for (int k = 1; k < 7; ++k) if (bid >= jobs.j[k].b0) ji = k;
    TCJ jb = jobs.j[ji];
    int local = bid - jb.b0;
    int bx = local % jb.nbx, by = local / jb.nbx;
    int c0 = bx * 32, r0 = by * 32;
    int col = threadIdx.x & 31, rw = threadIdx.x >> 5;
#pragma unroll
    for (int i = 0; i < 4; ++i) {
        int r = rw + i * 8;
        t[r][col] = jb.s[(size_t)(r0 + r) * jb.Ncol + c0 + col];
    }
    __syncthreads();
#pragma unroll
    for (int i = 0; i < 4; ++i) {
        int r = rw + i * 8;
        jb.d[(size_t)(c0 + r) * jb.R + r0 + col] = f2b(t[col][r]);
    }
}

// ------------------------------------------------ 256x256 GEMM core: 8 waves (2Mx4N), BK=64,
// double-buffered LDS (2 x 64KB), ONE barrier per K-tile, 64 MFMA per barrier.
// Buffer layout (u16): [A 16384][B 16384], buffer stride 32768.  Slot swizzle: g^(row&7).
__device__ __forceinline__ void gemm_core256(const u16* __restrict__ A,
                                             const u16* __restrict__ WT,
                                             int K, int m0, int n0,
                                             u16* L, f32x4 acc[8][4]) {
    const int tid = threadIdx.x;
    const int lane = tid & 63, wid = tid >> 6;
    const int wr = wid >> 2, wc = wid & 3;      // 2M x 4N
    const int r16 = lane & 15, g = lane >> 4;   // g = 0..3

    // staging: per instr 512 threads x 8 elems = 64 rows of [64K]; 4 instrs per matrix.
    const int srow = tid >> 3;                  // 0..63  (row&7 invariant under +64)
    const int sunit = tid & 7;                  // 0..7
    const int ssw = sunit ^ (srow & 7);         // inverse-swizzled global k-slot
    const u16* gA = A + (size_t)(m0 + srow) * K + ssw * 8;
    const u16* gB = WT + (size_t)(n0 + srow) * K + ssw * 8;
    u16* lA = L + tid * 8;
    u16* lB = L + 16384 + tid * 8;

#define STGA(buf) do { \
        gld_lds16(gA,                   lA + (buf) * 32768); \
        gld_lds16(gA + (size_t)64 * K,  lA + (buf) * 32768 + 4096); \
        gld_lds16(gA + (size_t)128 * K, lA + (buf) * 32768 + 8192); \
        gld_lds16(gA + (size_t)192 * K, lA + (buf) * 32768 + 12288); \
        gA += 64; } while (0)
#define STGB(buf) do { \
        gld_lds16(gB,                   lB + (buf) * 32768); \
        gld_lds16(gB + (size_t)64 * K,  lB + (buf) * 32768 + 4096); \
        gld_lds16(gB + (size_t)128 * K, lB + (buf) * 32768 + 8192); \
        gld_lds16(gB + (size_t)192 * K, lB + (buf) * 32768 + 12288); \
        gB += 64; } while (0)

    // fragment read offsets (u16 elems) for K-half 0; K-half 1 = off ^ 32
    int offA[8], offB[4];
#pragma unroll
    for (int m = 0; m < 8; ++m) {
        int row = wr * 128 + m * 16 + r16;
        offA[m] = row * 64 + (g ^ (row & 7)) * 8;
    }
#pragma unroll
    for (int n = 0; n < 4; ++n) {
        int rob = wc * 64 + n * 16 + r16;
        offB[n] = 16384 + rob * 64 + (g ^ (rob & 7)) * 8;
    }

    const int nt = K >> 6;
    // prologue: stage tile 0 into buffer 0
    STGA(0); STGB(0);
    asm volatile("s_waitcnt vmcnt(0)" ::: "memory");
    __builtin_amdgcn_sched_barrier(0);
    __builtin_amdgcn_s_barrier();

    for (int t = 0; t < nt; ++t) {
        const u16* Lb = L + (t & 1) * 32768;
        const bool stg = (t + 1 < nt);
        // ---- sub-phase 0: K-half 0 frags, then issue ALL staging for tile t+1
        bf16x8 a0[8], b0[4];
#pragma unroll
        for (int m = 0; m < 8; ++m) a0[m] = *(const bf16x8*)(Lb + offA[m]);
#pragma unroll
        for (int n = 0; n < 4; ++n) b0[n] = *(const bf16x8*)(Lb + offB[n]);
        __builtin_amdgcn_sched_barrier(0);
        if (stg) { STGA((t + 1) & 1); STGB((t + 1) & 1); }
        asm volatile("s_waitcnt lgkmcnt(0)" ::: "memory");
        __builtin_amdgcn_sched_barrier(0);
        __builtin_amdgcn_s_setprio(1);
#pragma unroll
        for (int m = 0; m < 8; ++m)
#pragma unroll
            for (int n = 0; n < 4; ++n)
                acc[m][n] = __builtin_amdgcn_mfma_f32_16x16x32_bf16(a0[m], b0[n], acc[m][n], 0, 0, 0);
        __builtin_amdgcn_s_setprio(0);
        __builtin_amdgcn_sched_barrier(0);
        // ---- sub-phase 1: K-half 1 frags (same buffer, off^32)
        bf16x8 a1[8], b1[4];
#pragma unroll
        for (int m = 0; m < 8; ++m) a1[m] = *(const bf16x8*)(Lb + (offA[m] ^ 32));
#pragma unroll
        for (int n = 0; n < 4; ++n) b1[n] = *(const bf16x8*)(Lb + (offB[n] ^ 32));
        asm volatile("s_waitcnt lgkmcnt(0)" ::: "memory");
        __builtin_amdgcn_sched_barrier(0);
        __builtin_amdgcn_s_setprio(1);
#pragma unroll
        for (int m = 0; m < 8; ++m)
#pragma unroll
            for (int n = 0; n < 4; ++n)
                acc[m][n] = __builtin_amdgcn_mfma_f32_16x16x32_bf16(a1[m], b1[n], acc[m][n], 0, 0, 0);
        __builtin_amdgcn_s_setprio(0);
        __builtin_amdgcn_sched_barrier(0);
        // ---- tile boundary: wait tile t+1 resident (issued ~64 MFMA ago), one barrier
        if (stg) {
            asm volatile("s_waitcnt vmcnt(0)" ::: "memory");
            __builtin_amdgcn_sched_barrier(0);
            __builtin_amdgcn_s_barrier();
        }
    }
#undef STGA
#undef STGB
}

// bijective XCD-chunked remap (m204), row-major within XCD (A-panel L2-resident)
__device__ __forceinline__ void xcd_remap2(int& bx, int& by) {
    const int gx = gridDim.x;
    const int nwg = gx * gridDim.y;
    const int lin = blockIdx.y * gx + blockIdx.x;
    const int q = nwg >> 3, r = nwg & 7;
    const int xcd = lin & 7, pos = lin >> 3;
    const int nid = (xcd < r ? xcd * (q + 1) : r * (q + 1) + (xcd - r) * q) + pos;
    bx = nid % gx;
    by = nid / gx;
}

__device__ __forceinline__ void epilogue256(f32x4 acc[8][4], u16* O, const u16* Emul,
                                            int m0, int n0, int N, int mode, bool emul) {
    const int lane = threadIdx.x & 63, wid = threadIdx.x >> 6;
    const int wr = wid >> 2, wc = wid & 3;
    const int r16 = lane & 15, g = lane >> 4;
#pragma unroll
    for (int m = 0; m < 8; ++m)
#pragma unroll
        for (int n = 0; n < 4; ++n)
#pragma unroll
            for (int j = 0; j < 4; ++j) {
                int row = m0 + wr * 128 + m * 16 + g * 4 + j;
                int col = n0 + wc * 64 + n * 16 + r16;
                float v = acc[m][n][j];
                if (mode == 1) v = 1.f / (1.f + expf(-v));
                else if (mode == 2) { v = fmaxf(v, 0.f); v = v * v; }
                size_t o = (size_t)row * N + col;
                if (emul) v *= b2f(Emul[o]);
                O[o] = f2b(v);
            }
}

// ------------------------------------------------ single GEMM (bf16 out), 256x256 tile
template<int MODE, bool EMUL>
__global__ __launch_bounds__(512, 1)
void gemm256(const u16* __restrict__ A, const u16* __restrict__ WT,
             u16* __restrict__ Cout, const u16* __restrict__ Emul, int N, int K) {
    __shared__ u16 L[65536];
    int bx, by;
    xcd_remap2(bx, by);
    const int m0 = by << 8, n0 = bx << 8;
    f32x4 acc[8][4];
#pragma unroll
    for (int i = 0; i < 8; ++i)
#pragma unroll
        for (int j = 0; j < 4; ++j)
#pragma unroll
            for (int q = 0; q < 4; ++q) acc[i][j][q] = 0.f;
    gemm_core256(A, WT, K, m0, n0, L, acc);
    epilogue256(acc, Cout, Emul, m0, n0, N, MODE, EMUL);
}

// ------------------------------------------------ fused K/V/R projections (blockIdx.z = slice)
struct P3 {
    const u16 *A0, *A1, *A2;
    const u16 *W0, *W1, *W2;
    u16 *O0, *O1, *O2;
};
__global__ __launch_bounds__(512, 1)
void proj3(P3 p, int N, int K) {
    __shared__ u16 L[65536];
    const int z = blockIdx.z;
    const u16* A = (z == 0) ? p.A0 : (z == 1) ? p.A1 : p.A2;
    const u16* W = (z == 0) ? p.W0 : (z == 1) ? p.W1 : p.W2;
    u16* O = (z == 0) ? p.O0 : (z == 1) ? p.O1 : p.O2;
    int bx, by;
    xcd_remap2(bx, by);
    const int m0 = by << 8, n0 = bx << 8;
    f32x4 acc[8][4];
#pragma unroll
    for (int i = 0; i < 8; ++i)
#pragma unroll
        for (int j = 0; j < 4; ++j)
#pragma unroll
            for (int q = 0; q < 4; ++q) acc[i][j][q] = 0.f;
    gemm_core256(A, W, K, m0, n0, L, acc);
    epilogue256(acc, O, nullptr, m0, n0, N, (z == 2) ? 1 : 0, false);
}

// ------------------------------------------------ fused FFN1 (relu^2) + Rr (sigmoid)
struct J2 {
    const u16 *A0, *W0; u16 *O0;   // FFN1: N=3072
    const u16 *A1, *W1; u16 *O1;   // Rr:   N=768
};
__global__ __launch_bounds__(512, 1)
void ffn1rr(J2 p, int K) {
    __shared__ u16 L[65536];
    int bx, by;
    xcd_remap2(bx, by);
    const bool isF = (bx < 12);
    const u16* A = isF ? p.A0 : p.A1;
    const u16* W = isF ? p.W0 : p.W1;
    u16* O = isF ? p.O0 : p.O1;
    const int N = isF ? 3072 : 768;
    const int m0 = by << 8;
    const int n0 = (isF ? bx : bx - 12) << 8;
    f32x4 acc[8][4];
#pragma unroll
    for (int i = 0; i < 8; ++i)
#pragma unroll
        for (int j = 0; j < 4; ++j)
#pragma unroll
            for (int q = 0; q < 4; ++q) acc[i][j][q] = 0.f;
    gemm_core256(A, W, K, m0, n0, L, acc);
    epilogue256(acc, O, nullptr, m0, n0, N, isF ? 2 : 1, false);
}

// ------------------------------------------------ WKV segmented scan
__global__ void wkv_p1(const float* __restrict__ td, const u16* __restrict__ K,
                       const u16* __restrict__ V, float* __restrict__ st) {
    int bc = blockIdx.x * 256 + threadIdx.x;
    int seg = blockIdx.y;
    int b = bc / C_, c = bc - b * C_;
    float w = -expf(td[c]);
    size_t off = (size_t)b * T_ * C_ + (size_t)seg * WSEG * C_ + c;
    float aa = 0.f, bb = 0.f, pp = -1e38f;
#pragma unroll 4
    for (int i = 0; i < WSEG; ++i) {
        float kt = b2f(K[off + (size_t)i * C_]);
        float vt = b2f(V[off + (size_t)i * C_]);
        float ww2 = pp + w;
        float p2 = fmaxf(ww2, kt);
        float e1 = expf(ww2 - p2);
        float e2 = expf(kt - p2);
        aa = e1 * aa + e2 * vt;
        bb = e1 * bb + e2;
        pp = p2;
    }
    int sidx = seg * 3 * BC_ + bc;
    st[sidx] = aa; st[sidx + BC_] = bb; st[sidx + 2 * BC_] = pp;
}

__global__ void wkv_p2(const float* __restrict__ td, const float* __restrict__ st,
                       float* __restrict__ ini) {
    int bc = blockIdx.x * 256 + threadIdx.x;
    int c = bc % C_;
    float wL = -expf(td[c]) * (float)WSEG;
    float aa = 0.f, bb = 0.f, pp = -1e38f;
    for (int s = 0; s < NWSEG; ++s) {
        int sidx = s * 3 * BC_ + bc;
        ini[sidx] = aa; ini[sidx + BC_] = bb; ini[sidx + 2 * BC_] = pp;
        float la = st[sidx], lb = st[sidx + BC_], lp = st[sidx + 2 * BC_];
        float ppw = pp + wL;
        float p = fmaxf(ppw, lp);
        float e1 = expf(ppw - p), e2 = expf(lp - p);
        aa = e1 * aa + e2 * la;
        bb = e1 * bb + e2 * lb;
        pp = p;
    }
}

// p3 applies the sigmoid(R) gate: writes RY = R * y
__global__ void wkv_p3(const float* __restrict__ td, const float* __restrict__ tf,
                       const u16* __restrict__ K, const u16* __restrict__ V,
                       const u16* __restrict__ R, const float* __restrict__ ini,
                       u16* __restrict__ RY) {
    int bc = blockIdx.x * 256 + threadIdx.x;
    int seg = blockIdx.y;
    int b = bc / C_, c = bc - b * C_;
    float w = -expf(td[c]);
    float u = tf[c];
    int sidx = seg * 3 * BC_ + bc;
    float aa = ini[sidx], bb = ini[sidx + BC_], pp = ini[sidx + 2 * BC_];
    size_t off = (size_t)b * T_ * C_ + (size_t)seg * WSEG * C_ + c;
#pragma unroll 4
    for (int i = 0; i < WSEG; ++i) {
        float kt = b2f(K[off + (size_t)i * C_]);
        float vt = b2f(V[off + (size_t)i * C_]);
        float rr = b2f(R[off + (size_t)i * C_]);
        float ww = u + kt;
        float p = fmaxf(pp, ww);
        float e1 = expf(pp - p);
        float e2 = expf(ww - p);
        RY[off + (size_t)i * C_] = f2b(rr * (e1 * aa + e2 * vt) / (e1 * bb + e2));
        float ww2 = pp + w;
        float p2 = fmaxf(ww2, kt);
        float e1b = expf(ww2 - p2);
        float e2b = expf(kt - p2);
        aa = e1b * aa + e2b * vt;
        bb = e1b * bb + e2b;
        pp = p2;
    }
}

// ------------------------------------------------ LIF + residual (bf16 input, segmented warm-up)
__global__ void lif_add_b(const u16* __restrict__ cur, const float* __restrict__ base,
                          float* __restrict__ out) {
    int bc = blockIdx.x * 256 + threadIdx.x;
    int seg = blockIdx.y;
    int b = bc / C_, c = bc - b * C_;
    size_t rowbase = (size_t)b * T_ * C_ + c;
    int t0 = seg * LSEG;
    int tw = t0 - LWARM; if (tw < 0) tw = 0;
    int nw = t0 - tw;
    float v = 0.f;
    const u16* cp = cur + rowbase + (size_t)tw * C_;
#pragma unroll 8
    for (int i = 0; i < nw; ++i) {
        float xt = b2f(cp[(size_t)i * C_]);
        v += (xt - v) * 0.5f;
        v = (v >= 1.f) ? 0.f : v;
    }
    const u16* c2 = cur + rowbase + (size_t)t0 * C_;
    const float* bp = base + rowbase + (size_t)t0 * C_;
    float* op = out + rowbase + (size_t)t0 * C_;
#pragma unroll 8
    for (int i = 0; i < LSEG; ++i) {
        float xt = b2f(c2[(size_t)i * C_]);
        v += (xt - v) * 0.5f;
        float sp = (v >= 1.f) ? 1.f : 0.f;
        op[(size_t)i * C_] = bp[(size_t)i * C_] + sp;
        v = (sp > 0.f) ? 0.f : v;
    }
}

// ------------------------------------------------ launcher
extern "C" void kernel_launch(void* const* d_in, const int* in_sizes, int n_in,
                              void* d_out, int out_size, void* d_ws, size_t ws_size,
                              hipStream_t stream) {
    const float* x    = (const float*)d_in[0];
    const float* ln1w = (const float*)d_in[1];
    const float* ln1b = (const float*)d_in[2];
    const float* ln2w = (const float*)d_in[3];
    const float* ln2b = (const float*)d_in[4];
    const float* td   = (const float*)d_in[5];
    const float* tf   = (const float*)d_in[6];
    const float* amk  = (const float*)d_in[7];
    const float* amv  = (const float*)d_in[8];
    const float* amr  = (const float*)d_in[9];
    const float* aWk  = (const float*)d_in[10];
    const float* aWv  = (const float*)d_in[11];
    const float* aWr  = (const float*)d_in[12];
    const float* aWo  = (const float*)d_in[13];
    const float* fmk  = (const float*)d_in[14];
    const float* fmr  = (const float*)d_in[15];
    const float* fWk  = (const float*)d_in[16];
    const float* fWv  = (const float*)d_in[17];
    const float* fWr  = (const float*)d_in[18];
    float* out = (float*)d_out;

    const size_t NBC = (size_t)BT_ * C_;
    u16* WkT = (u16*)d_ws;
    u16* WvT = WkT + 589824;
    u16* WrT = WvT + 589824;
    u16* WoT = WrT + 589824;
    u16* FrT = WoT + 589824;
    u16* FkT = FrT + 589824;                  // [3072][768]
    u16* FvT = FkT + 2359296;                 // [768][3072]
    float* st  = (float*)(FvT + 2359296);
    float* ini = st + NWSEG * 3 * BC_;
    u16* S0 = (u16*)(ini + NWSEG * 3 * BC_);
    u16* S1 = S0 + NBC;
    u16* S2 = S1 + NBC;
    u16* S3 = S2 + NBC;
    u16* Hbuf = S3 + NBC;
    size_t fixed_b = (size_t)((char*)Hbuf - (char*)d_ws);

    // FFN chunking (H bf16 chunk + F bf16 chunk after it)
    int NCH = 4;
    if (ws_size >= fixed_b + ((size_t)BT_ * H_ + NBC) * 2) NCH = 1;
    else if (ws_size >= fixed_b + ((size_t)(BT_ / 2) * H_ + NBC / 2) * 2) NCH = 2;
    const int CH = BT_ / NCH;
    u16* Fbuf = Hbuf + (size_t)CH * H_;

    u16* Kb = (u16*)d_out;
    u16* Vb = Kb + NBC;

    // 0. weights -> bf16 [N][K] (one batched dispatch)
    {
        TC7 jobs;
        const float* srcs[7] = {aWk, aWv, aWr, aWo, fWr, fWk, fWv};
        u16* dsts[7] = {WkT, WvT, WrT, WoT, FrT, FkT, FvT};
        int Rs[7]    = {768, 768, 768, 768, 768, 768, 3072};
        int Ns[7]    = {768, 768, 768, 768, 768, 3072, 768};
        int b0 = 0;
        for (int k = 0; k < 7; ++k) {
            jobs.j[k].s = srcs[k]; jobs.j[k].d = dsts[k];
            jobs.j[k].R = Rs[k]; jobs.j[k].Ncol = Ns[k];
            jobs.j[k].nbx = Ns[k] / 32; jobs.j[k].b0 = b0;
            b0 += (Ns[k] / 32) * (Rs[k] / 32);
        }
        tcast_all<<<b0, 256, 0, stream>>>(jobs);
    }

    // 1. xk,xv,xr = mix(ln1(x)) -> S0,S1,S2
    lnmix<3><<<BT_, 256, 0, stream>>>(x, ln1w, ln1b, amk, amv, amr, S0, S1, S2);
    // 2. K,V,sigmoid(R) in one fused dispatch (256^2 tiles)
    {
        P3 p{S0, S1, S2, WkT, WvT, WrT, Kb, Vb, S3};
        proj3<<<dim3(3, 64, 3), 512, 0, stream>>>(p, C_, C_);
    }
    // 3. RY = sigmoid(R) * wkv(K,V) -> S0
    wkv_p1<<<dim3(BC_ / 256, NWSEG), 256, 0, stream>>>(td, Kb, Vb, st);
    wkv_p2<<<BC_ / 256, 256, 0, stream>>>(td, st, ini);
    wkv_p3<<<dim3(BC_ / 256, NWSEG), 256, 0, stream>>>(td, tf, Kb, Vb, S3, ini, S0);
    // 4. A_out = RY @ Wo -> bf16 S1
    gemm256<0, false><<<dim3(3, 64), 512, 0, stream>>>(S0, WoT, S1, nullptr, C_, C_);
    // 5. X2 = x + lif(A_out) -> d_out
    lif_add_b<<<dim3(BC_ / 256, NLSEG), 256, 0, stream>>>(S1, x, out);
    // 6. xk2 -> S0, xr2 -> S1
    lnmix<2><<<BT_, 256, 0, stream>>>(out, ln2w, ln2b, fmk, fmr, nullptr, S0, S1, nullptr);

    if (NCH == 1) {
        // 7. fused: H = relu^2(xk2 @ fWk), RR = sigmoid(xr2 @ fWr)
        J2 p{S0, FkT, Hbuf, S1, FrT, S2};
        ffn1rr<<<dim3(15, 64), 512, 0, stream>>>(p, C_);
        // 8. F = RR * (H @ fWv) -> Fbuf; out += lif(F)
        gemm256<0, true><<<dim3(3, 64), 512, 0, stream>>>(Hbuf, FvT, Fbuf, S2, C_, H_);
        lif_add_b<<<dim3(BC_ / 256, NLSEG), 256, 0, stream>>>(Fbuf, out, out);
    } else {
        // 7. RR = sigmoid(xr2 @ fWr) -> S2
        gemm256<1, false><<<dim3(3, 64), 512, 0, stream>>>(S1, FrT, S2, nullptr, C_, C_);
        // 8. FFN per chunk
        for (int ch = 0; ch < NCH; ++ch) {
            const u16* xk2c = S0 + (size_t)ch * CH * C_;
            const u16* rrc  = S2 + (size_t)ch * CH * C_;
            gemm256<2, false><<<dim3(12, CH / 256), 512, 0, stream>>>(xk2c, FkT, Hbuf, nullptr, H_, C_);
            gemm256<0, true><<<dim3(3, CH / 256), 512, 0, stream>>>(Hbuf, FvT, Fbuf, rrc, C_, H_);
            lif_add_b<<<dim3((CH / T_) * C_ / 256, NLSEG), 256, 0, stream>>>(
                Fbuf, out + (size_t)ch * CH * C_, out + (size_t)ch * CH * C_);
        }
    }
}

// Round 13
// 563.893 us; speedup vs baseline: 1.0730x; 1.0127x over previous
//
#include <hip/hip_runtime.h>

#define B_ 8
#define T_ 2048
#define C_ 768
#define H_ 3072
#define BT_ (B_ * T_)
#define BC_ (B_ * C_)
#define WSEG 128
#define NWSEG 16
#define LSEG 128
#define NLSEG 16
#define LWARM 96

typedef unsigned short u16;
typedef short bf16x8 __attribute__((ext_vector_type(8)));
typedef float f32x4 __attribute__((ext_vector_type(4)));

__device__ __forceinline__ float b2f(u16 u) {
    union { unsigned i; float f; } w; w.i = ((unsigned)u) << 16; return w.f;
}
__device__ __forceinline__ u16 f2b(float f) {
    union { float f; unsigned i; } w; w.f = f;
    return (u16)((w.i + 0x7fffu + ((w.i >> 16) & 1u)) >> 16);
}

typedef __attribute__((address_space(3))) unsigned int lds_u32;
typedef const __attribute__((address_space(1))) unsigned int glb_u32;
__device__ __forceinline__ void gld_lds16(const void* g, void* l) {
    __builtin_amdgcn_global_load_lds((glb_u32*)g, (lds_u32*)l, 16, 0, 0);
}

// ------------------------------------------------ LayerNorm + token-shift mix (f32 in, bf16 out)
template<int NOUT>
__global__ void lnmix(const float* __restrict__ x, const float* __restrict__ w,
                      const float* __restrict__ b,
                      const float* __restrict__ m1, const float* __restrict__ m2,
                      const float* __restrict__ m3,
                      u16* __restrict__ o1, u16* __restrict__ o2, u16* __restrict__ o3) {
    int row = blockIdx.x;
    int t = row % T_;
    const float* xr = x + (size_t)row * C_;
    const float* xp = xr - C_;
    int tid = threadIdx.x;
    float s = 0.f, s2 = 0.f, ps = 0.f, ps2 = 0.f;
    for (int i = tid; i < C_; i += 256) {
        float v = xr[i]; s += v; s2 += v * v;
        if (t > 0) { float u = xp[i]; ps += u; ps2 += u * u; }
    }
    for (int off = 32; off > 0; off >>= 1) {
        s += __shfl_down(s, off);  s2 += __shfl_down(s2, off);
        ps += __shfl_down(ps, off); ps2 += __shfl_down(ps2, off);
    }
    __shared__ float red[4][4];
    int wid = tid >> 6, lane = tid & 63;
    if (lane == 0) { red[wid][0] = s; red[wid][1] = s2; red[wid][2] = ps; red[wid][3] = ps2; }
    __syncthreads();
    if (tid == 0) {
        float a0 = 0, a1 = 0, a2 = 0, a3 = 0;
        for (int i = 0; i < 4; ++i) { a0 += red[i][0]; a1 += red[i][1]; a2 += red[i][2]; a3 += red[i][3]; }
        red[0][0] = a0; red[0][1] = a1; red[0][2] = a2; red[0][3] = a3;
    }
    __syncthreads();
    float mu = red[0][0] * (1.f / C_);
    float rs = rsqrtf(red[0][1] * (1.f / C_) - mu * mu + 1e-5f);
    float pmu = red[0][2] * (1.f / C_);
    float prs = rsqrtf(red[0][3] * (1.f / C_) - pmu * pmu + 1e-5f);
    size_t ob = (size_t)row * C_;
    for (int i = tid; i < C_; i += 256) {
        float wi = w[i], bi = b[i];
        float n = (xr[i] - mu) * rs * wi + bi;
        float np = (t > 0) ? (xp[i] - pmu) * prs * wi + bi : 0.f;
        o1[ob + i] = f2b(fmaf(m1[i], n - np, np));
        o2[ob + i] = f2b(fmaf(m2[i], n - np, np));
        if constexpr (NOUT == 3) o3[ob + i] = f2b(fmaf(m3[i], n - np, np));
    }
}

// ------------------------------------------------ batched transpose-cast f32[R][N] -> bf16[N][R]
struct TCJ { const float* s; u16* d; int R, Ncol, nbx, b0; };
struct TC7 { TCJ j[7]; };
__global__ void tcast_all(TC7 jobs) {
    __shared__ float t[32][33];
    int bid = blockIdx.x;
    int ji = 0;
#pragma unroll
    for (int k = 1; k < 7; ++k) if (bid >= jobs.j[k].b0) ji = k;
    TCJ jb = jobs.j[ji];
    int local = bid - jb.b0;
    int bx = local % jb.nbx, by = local / jb.nbx;
    int c0 = bx * 32, r0 = by * 32;
    int col = threadIdx.x & 31, rw = threadIdx.x >> 5;
#pragma unroll
    for (int i = 0; i < 4; ++i) {
        int r = rw + i * 8;
        t[r][col] = jb.s[(size_t)(r0 + r) * jb.Ncol + c0 + col];
    }
    __syncthreads();
#pragma unroll
    for (int i = 0; i < 4; ++i) {
        int r = rw + i * 8;
        jb.d[(size_t)(c0 + r) * jb.R + r0 + col] = f2b(t[col][r]);
    }
}

// ------------------------------------------------ 256x256 GEMM core: 8 waves (2Mx4N), BK=64,
// double-buffered LDS (2 x 64KB), ONE barrier per K-tile, 64 MFMA per barrier.
__device__ __forceinline__ void gemm_core256(const u16* __restrict__ A,
                                             const u16* __restrict__ WT,
                                             int K, int m0, int n0,
                                             u16* L, f32x4 acc[8][4]) {
    const int tid = threadIdx.x;
    const int lane = tid & 63, wid = tid >> 6;
    const int wr = wid >> 2, wc = wid & 3;      // 2M x 4N
    const int r16 = lane & 15, g = lane >> 4;   // g = 0..3

    const int srow = tid >> 3;                  // 0..63  (row&7 invariant under +64)
    const int sunit = tid & 7;                  // 0..7
    const int ssw = sunit ^ (srow & 7);         // inverse-swizzled global k-slot
    const u16* gA = A + (size_t)(m0 + srow) * K + ssw * 8;
    const u16* gB = WT + (size_t)(n0 + srow) * K + ssw * 8;
    u16* lA = L + tid * 8;
    u16* lB = L + 16384 + tid * 8;

#define STGA(buf) do { \
        gld_lds16(gA,                   lA + (buf) * 32768); \
        gld_lds16(gA + (size_t)64 * K,  lA + (buf) * 32768 + 4096); \
        gld_lds16(gA + (size_t)128 * K, lA + (buf) * 32768 + 8192); \
        gld_lds16(gA + (size_t)192 * K, lA + (buf) * 32768 + 12288); \
        gA += 64; } while (0)
#define STGB(buf) do { \
        gld_lds16(gB,                   lB + (buf) * 32768); \
        gld_lds16(gB + (size_t)64 * K,  lB + (buf) * 32768 + 4096); \
        gld_lds16(gB + (size_t)128 * K, lB + (buf) * 32768 + 8192); \
        gld_lds16(gB + (size_t)192 * K, lB + (buf) * 32768 + 12288); \
        gB += 64; } while (0)

    int offA[8], offB[4];
#pragma unroll
    for (int m = 0; m < 8; ++m) {
        int row = wr * 128 + m * 16 + r16;
        offA[m] = row * 64 + (g ^ (row & 7)) * 8;
    }
#pragma unroll
    for (int n = 0; n < 4; ++n) {
        int rob = wc * 64 + n * 16 + r16;
        offB[n] = 16384 + rob * 64 + (g ^ (rob & 7)) * 8;
    }

    const int nt = K >> 6;
    STGA(0); STGB(0);
    asm volatile("s_waitcnt vmcnt(0)" ::: "memory");
    __builtin_amdgcn_sched_barrier(0);
    __builtin_amdgcn_s_barrier();

    for (int t = 0; t < nt; ++t) {
        const u16* Lb = L + (t & 1) * 32768;
        const bool stg = (t + 1 < nt);
        bf16x8 a0[8], b0[4];
#pragma unroll
        for (int m = 0; m < 8; ++m) a0[m] = *(const bf16x8*)(Lb + offA[m]);
#pragma unroll
        for (int n = 0; n < 4; ++n) b0[n] = *(const bf16x8*)(Lb + offB[n]);
        __builtin_amdgcn_sched_barrier(0);
        if (stg) { STGA((t + 1) & 1); STGB((t + 1) & 1); }
        asm volatile("s_waitcnt lgkmcnt(0)" ::: "memory");
        __builtin_amdgcn_sched_barrier(0);
        __builtin_amdgcn_s_setprio(1);
#pragma unroll
        for (int m = 0; m < 8; ++m)
#pragma unroll
            for (int n = 0; n < 4; ++n)
                acc[m][n] = __builtin_amdgcn_mfma_f32_16x16x32_bf16(a0[m], b0[n], acc[m][n], 0, 0, 0);
        __builtin_amdgcn_s_setprio(0);
        __builtin_amdgcn_sched_barrier(0);
        bf16x8 a1[8], b1[4];
#pragma unroll
        for (int m = 0; m < 8; ++m) a1[m] = *(const bf16x8*)(Lb + (offA[m] ^ 32));
#pragma unroll
        for (int n = 0; n < 4; ++n) b1[n] = *(const bf16x8*)(Lb + (offB[n] ^ 32));
        asm volatile("s_waitcnt lgkmcnt(0)" ::: "memory");
        __builtin_amdgcn_sched_barrier(0);
        __builtin_amdgcn_s_setprio(1);
#pragma unroll
        for (int m = 0; m < 8; ++m)
#pragma unroll
            for (int n = 0; n < 4; ++n)
                acc[m][n] = __builtin_amdgcn_mfma_f32_16x16x32_bf16(a1[m], b1[n], acc[m][n], 0, 0, 0);
        __builtin_amdgcn_s_setprio(0);
        __builtin_amdgcn_sched_barrier(0);
        if (stg) {
            asm volatile("s_waitcnt vmcnt(0)" ::: "memory");
            __builtin_amdgcn_sched_barrier(0);
            __builtin_amdgcn_s_barrier();
        }
    }
#undef STGA
#undef STGB
}

// bijective XCD-chunked remap (m204) + GROUP_M=4 super-tiling:
// the 32 concurrently-resident blocks per XCD cover 4 rows x 8 cols ->
// concurrent L2 working set = 4 A-panels + 8 B-panels (~4.5MB, fits 4MB-ish L2)
__device__ __forceinline__ void xcd_remap2(int& bx, int& by) {
    const int gx = gridDim.x;
    const int nwg = gx * gridDim.y;
    const int lin = blockIdx.y * gx + blockIdx.x;
    const int q = nwg >> 3, r = nwg & 7;
    const int xcd = lin & 7, pos = lin >> 3;
    const int nid = (xcd < r ? xcd * (q + 1) : r * (q + 1) + (xcd - r) * q) + pos;
    const int g4 = gx << 2;
    const int grp = nid / g4, rem = nid - grp * g4;
    by = (grp << 2) + (rem & 3);
    bx = rem >> 2;
}

__device__ __forceinline__ void epilogue256(f32x4 acc[8][4], u16* O, const u16* Emul,
                                            int m0, int n0, int N, int mode, bool emul) {
    const int lane = threadIdx.x & 63, wid = threadIdx.x >> 6;
    const int wr = wid >> 2, wc = wid & 3;
    const int r16 = lane & 15, g = lane >> 4;
#pragma unroll
    for (int m = 0; m < 8; ++m)
#pragma unroll
        for (int n = 0; n < 4; ++n)
#pragma unroll
            for (int j = 0; j < 4; ++j) {
                int row = m0 + wr * 128 + m * 16 + g * 4 + j;
                int col = n0 + wc * 64 + n * 16 + r16;
                float v = acc[m][n][j];
                if (mode == 1) v = 1.f / (1.f + expf(-v));
                else if (mode == 2) { v = fmaxf(v, 0.f); v = v * v; }
                size_t o = (size_t)row * N + col;
                if (emul) v *= b2f(Emul[o]);
                O[o] = f2b(v);
            }
}

// ------------------------------------------------ single GEMM (bf16 out), 256x256 tile
template<int MODE, bool EMUL>
__global__ __launch_bounds__(512, 1)
void gemm256(const u16* __restrict__ A, const u16* __restrict__ WT,
             u16* __restrict__ Cout, const u16* __restrict__ Emul, int N, int K) {
    __shared__ u16 L[65536];
    int bx, by;
    xcd_remap2(bx, by);
    const int m0 = by << 8, n0 = bx << 8;
    f32x4 acc[8][4];
#pragma unroll
    for (int i = 0; i < 8; ++i)
#pragma unroll
        for (int j = 0; j < 4; ++j)
#pragma unroll
            for (int q = 0; q < 4; ++q) acc[i][j][q] = 0.f;
    gemm_core256(A, WT, K, m0, n0, L, acc);
    epilogue256(acc, Cout, Emul, m0, n0, N, MODE, EMUL);
}

// ------------------------------------------------ fused K/V/R projections (blockIdx.z = slice)
struct P3 {
    const u16 *A0, *A1, *A2;
    const u16 *W0, *W1, *W2;
    u16 *O0, *O1, *O2;
};
__global__ __launch_bounds__(512, 1)
void proj3(P3 p, int N, int K) {
    __shared__ u16 L[65536];
    const int z = blockIdx.z;
    const u16* A = (z == 0) ? p.A0 : (z == 1) ? p.A1 : p.A2;
    const u16* W = (z == 0) ? p.W0 : (z == 1) ? p.W1 : p.W2;
    u16* O = (z == 0) ? p.O0 : (z == 1) ? p.O1 : p.O2;
    int bx, by;
    xcd_remap2(bx, by);
    const int m0 = by << 8, n0 = bx << 8;
    f32x4 acc[8][4];
#pragma unroll
    for (int i = 0; i < 8; ++i)
#pragma unroll
        for (int j = 0; j < 4; ++j)
#pragma unroll
            for (int q = 0; q < 4; ++q) acc[i][j][q] = 0.f;
    gemm_core256(A, W, K, m0, n0, L, acc);
    epilogue256(acc, O, nullptr, m0, n0, N, (z == 2) ? 1 : 0, false);
}

// ------------------------------------------------ fused FFN1 (relu^2) + Rr (sigmoid)
struct J2 {
    const u16 *A0, *W0; u16 *O0;   // FFN1: N=3072
    const u16 *A1, *W1; u16 *O1;   // Rr:   N=768
};
__global__ __launch_bounds__(512, 1)
void ffn1rr(J2 p, int K) {
    __shared__ u16 L[65536];
    int bx, by;
    xcd_remap2(bx, by);
    const bool isF = (bx < 12);
    const u16* A = isF ? p.A0 : p.A1;
    const u16* W = isF ? p.W0 : p.W1;
    u16* O = isF ? p.O0 : p.O1;
    const int N = isF ? 3072 : 768;
    const int m0 = by << 8;
    const int n0 = (isF ? bx : bx - 12) << 8;
    f32x4 acc[8][4];
#pragma unroll
    for (int i = 0; i < 8; ++i)
#pragma unroll
        for (int j = 0; j < 4; ++j)
#pragma unroll
            for (int q = 0; q < 4; ++q) acc[i][j][q] = 0.f;
    gemm_core256(A, W, K, m0, n0, L, acc);
    epilogue256(acc, O, nullptr, m0, n0, N, isF ? 2 : 1, false);
}

// ------------------------------------------------ WKV segmented scan
__global__ void wkv_p1(const float* __restrict__ td, const u16* __restrict__ K,
                       const u16* __restrict__ V, float* __restrict__ st) {
    int bc = blockIdx.x * 256 + threadIdx.x;
    int seg = blockIdx.y;
    int b = bc / C_, c = bc - b * C_;
    float w = -expf(td[c]);
    size_t off = (size_t)b * T_ * C_ + (size_t)seg * WSEG * C_ + c;
    float aa = 0.f, bb = 0.f, pp = -1e38f;
#pragma unroll 4
    for (int i = 0; i < WSEG; ++i) {
        float kt = b2f(K[off + (size_t)i * C_]);
        float vt = b2f(V[off + (size_t)i * C_]);
        float ww2 = pp + w;
        float p2 = fmaxf(ww2, kt);
        float e1 = expf(ww2 - p2);
        float e2 = expf(kt - p2);
        aa = e1 * aa + e2 * vt;
        bb = e1 * bb + e2;
        pp = p2;
    }
    int sidx = seg * 3 * BC_ + bc;
    st[sidx] = aa; st[sidx + BC_] = bb; st[sidx + 2 * BC_] = pp;
}

// p3 composes its own segment-prefix from st (p2 folded in) and applies sigmoid(R) gate
__global__ void wkv_p3(const float* __restrict__ td, const float* __restrict__ tf,
                       const u16* __restrict__ K, const u16* __restrict__ V,
                       const u16* __restrict__ R, const float* __restrict__ st,
                       u16* __restrict__ RY) {
    int bc = blockIdx.x * 256 + threadIdx.x;
    int seg = blockIdx.y;
    int b = bc / C_, c = bc - b * C_;
    float w = -expf(td[c]);
    float u = tf[c];
    float wL = w * (float)WSEG;
    // prefix over segments [0, seg)
    float aa = 0.f, bb = 0.f, pp = -1e38f;
    for (int s = 0; s < seg; ++s) {
        int sidx = s * 3 * BC_ + bc;
        float la = st[sidx], lb = st[sidx + BC_], lp = st[sidx + 2 * BC_];
        float ppw = pp + wL;
        float p = fmaxf(ppw, lp);
        float e1 = expf(ppw - p), e2 = expf(lp - p);
        aa = e1 * aa + e2 * la;
        bb = e1 * bb + e2 * lb;
        pp = p;
    }
    size_t off = (size_t)b * T_ * C_ + (size_t)seg * WSEG * C_ + c;
#pragma unroll 4
    for (int i = 0; i < WSEG; ++i) {
        float kt = b2f(K[off + (size_t)i * C_]);
        float vt = b2f(V[off + (size_t)i * C_]);
        float rr = b2f(R[off + (size_t)i * C_]);
        float ww = u + kt;
        float p = fmaxf(pp, ww);
        float e1 = expf(pp - p);
        float e2 = expf(ww - p);
        RY[off + (size_t)i * C_] = f2b(rr * (e1 * aa + e2 * vt) / (e1 * bb + e2));
        float ww2 = pp + w;
        float p2 = fmaxf(ww2, kt);
        float e1b = expf(ww2 - p2);
        float e2b = expf(kt - p2);
        aa = e1b * aa + e2b * vt;
        bb = e1b * bb + e2b;
        pp = p2;
    }
}

// ------------------------------------------------ LIF + residual (bf16 input, segmented warm-up)
__global__ void lif_add_b(const u16* __restrict__ cur, const float* __restrict__ base,
                          float* __restrict__ out) {
    int bc = blockIdx.x * 256 + threadIdx.x;
    int seg = blockIdx.y;
    int b = bc / C_, c = bc - b * C_;
    size_t rowbase = (size_t)b * T_ * C_ + c;
    int t0 = seg * LSEG;
    int tw = t0 - LWARM; if (tw < 0) tw = 0;
    int nw = t0 - tw;
    float v = 0.f;
    const u16* cp = cur + rowbase + (size_t)tw * C_;
#pragma unroll 8
    for (int i = 0; i < nw; ++i) {
        float xt = b2f(cp[(size_t)i * C_]);
        v += (xt - v) * 0.5f;
        v = (v >= 1.f) ? 0.f : v;
    }
    const u16* c2 = cur + rowbase + (size_t)t0 * C_;
    const float* bp = base + rowbase + (size_t)t0 * C_;
    float* op = out + rowbase + (size_t)t0 * C_;
#pragma unroll 8
    for (int i = 0; i < LSEG; ++i) {
        float xt = b2f(c2[(size_t)i * C_]);
        v += (xt - v) * 0.5f;
        float sp = (v >= 1.f) ? 1.f : 0.f;
        op[(size_t)i * C_] = bp[(size_t)i * C_] + sp;
        v = (sp > 0.f) ? 0.f : v;
    }
}

// ------------------------------------------------ launcher
extern "C" void kernel_launch(void* const* d_in, const int* in_sizes, int n_in,
                              void* d_out, int out_size, void* d_ws, size_t ws_size,
                              hipStream_t stream) {
    const float* x    = (const float*)d_in[0];
    const float* ln1w = (const float*)d_in[1];
    const float* ln1b = (const float*)d_in[2];
    const float* ln2w = (const float*)d_in[3];
    const float* ln2b = (const float*)d_in[4];
    const float* td   = (const float*)d_in[5];
    const float* tf   = (const float*)d_in[6];
    const float* amk  = (const float*)d_in[7];
    const float* amv  = (const float*)d_in[8];
    const float* amr  = (const float*)d_in[9];
    const float* aWk  = (const float*)d_in[10];
    const float* aWv  = (const float*)d_in[11];
    const float* aWr  = (const float*)d_in[12];
    const float* aWo  = (const float*)d_in[13];
    const float* fmk  = (const float*)d_in[14];
    const float* fmr  = (const float*)d_in[15];
    const float* fWk  = (const float*)d_in[16];
    const float* fWv  = (const float*)d_in[17];
    const float* fWr  = (const float*)d_in[18];
    float* out = (float*)d_out;

    const size_t NBC = (size_t)BT_ * C_;
    u16* WkT = (u16*)d_ws;
    u16* WvT = WkT + 589824;
    u16* WrT = WvT + 589824;
    u16* WoT = WrT + 589824;
    u16* FrT = WoT + 589824;
    u16* FkT = FrT + 589824;                  // [3072][768]
    u16* FvT = FkT + 2359296;                 // [768][3072]
    float* st  = (float*)(FvT + 2359296);
    u16* S0 = (u16*)(st + NWSEG * 3 * BC_);
    u16* S1 = S0 + NBC;
    u16* S2 = S1 + NBC;
    u16* S3 = S2 + NBC;
    u16* Hbuf = S3 + NBC;
    size_t fixed_b = (size_t)((char*)Hbuf - (char*)d_ws);

    // FFN chunking (H bf16 chunk + F bf16 chunk after it)
    int NCH = 4;
    if (ws_size >= fixed_b + ((size_t)BT_ * H_ + NBC) * 2) NCH = 1;
    else if (ws_size >= fixed_b + ((size_t)(BT_ / 2) * H_ + NBC / 2) * 2) NCH = 2;
    const int CH = BT_ / NCH;
    u16* Fbuf = Hbuf + (size_t)CH * H_;

    u16* Kb = (u16*)d_out;
    u16* Vb = Kb + NBC;

    // 0. weights -> bf16 [N][K] (one batched dispatch)
    {
        TC7 jobs;
        const float* srcs[7] = {aWk, aWv, aWr, aWo, fWr, fWk, fWv};
        u16* dsts[7] = {WkT, WvT, WrT, WoT, FrT, FkT, FvT};
        int Rs[7]    = {768, 768, 768, 768, 768, 768, 3072};
        int Ns[7]    = {768, 768, 768, 768, 768, 3072, 768};
        int b0 = 0;
        for (int k = 0; k < 7; ++k) {
            jobs.j[k].s = srcs[k]; jobs.j[k].d = dsts[k];
            jobs.j[k].R = Rs[k]; jobs.j[k].Ncol = Ns[k];
            jobs.j[k].nbx = Ns[k] / 32; jobs.j[k].b0 = b0;
            b0 += (Ns[k] / 32) * (Rs[k] / 32);
        }
        tcast_all<<<b0, 256, 0, stream>>>(jobs);
    }

    // 1. xk,xv,xr = mix(ln1(x)) -> S0,S1,S2
    lnmix<3><<<BT_, 256, 0, stream>>>(x, ln1w, ln1b, amk, amv, amr, S0, S1, S2);
    // 2. K,V,sigmoid(R) in one fused dispatch (256^2 tiles)
    {
        P3 p{S0, S1, S2, WkT, WvT, WrT, Kb, Vb, S3};
        proj3<<<dim3(3, 64, 3), 512, 0, stream>>>(p, C_, C_);
    }
    // 3. RY = sigmoid(R) * wkv(K,V) -> S0   (p2 folded into p3)
    wkv_p1<<<dim3(BC_ / 256, NWSEG), 256, 0, stream>>>(td, Kb, Vb, st);
    wkv_p3<<<dim3(BC_ / 256, NWSEG), 256, 0, stream>>>(td, tf, Kb, Vb, S3, st, S0);
    // 4. A_out = RY @ Wo -> bf16 S1
    gemm256<0, false><<<dim3(3, 64), 512, 0, stream>>>(S0, WoT, S1, nullptr, C_, C_);
    // 5. X2 = x + lif(A_out) -> d_out
    lif_add_b<<<dim3(BC_ / 256, NLSEG), 256, 0, stream>>>(S1, x, out);
    // 6. xk2 -> S0, xr2 -> S1
    lnmix<2><<<BT_, 256, 0, stream>>>(out, ln2w, ln2b, fmk, fmr, nullptr, S0, S1, nullptr);

    if (NCH == 1) {
        // 7. fused: H = relu^2(xk2 @ fWk), RR = sigmoid(xr2 @ fWr)
        J2 p{S0, FkT, Hbuf, S1, FrT, S2};
        ffn1rr<<<dim3(15, 64), 512, 0, stream>>>(p, C_);
        // 8. F = RR * (H @ fWv) -> Fbuf; out += lif(F)
        gemm256<0, true><<<dim3(3, 64), 512, 0, stream>>>(Hbuf, FvT, Fbuf, S2, C_, H_);
        lif_add_b<<<dim3(BC_ / 256, NLSEG), 256, 0, stream>>>(Fbuf, out, out);
    } else {
        // 7. RR = sigmoid(xr2 @ fWr) -> S2
        gemm256<1, false><<<dim3(3, 64), 512, 0, stream>>>(S1, FrT, S2, nullptr, C_, C_);
        // 8. FFN per chunk
        for (int ch = 0; ch < NCH; ++ch) {
            const u16* xk2c = S0 + (size_t)ch * CH * C_;
            const u16* rrc  = S2 + (size_t)ch * CH * C_;
            gemm256<2, false><<<dim3(12, CH / 256), 512, 0, stream>>>(xk2c, FkT, Hbuf, nullptr, H_, C_);
            gemm256<0, true><<<dim3(3, CH / 256), 512, 0, stream>>>(Hbuf, FvT, Fbuf, rrc, C_, H_);
            lif_add_b<<<dim3((CH / T_) * C_ / 256, NLSEG), 256, 0, stream>>>(
                Fbuf, out + (size_t)ch * CH * C_, out + (size_t)ch * CH * C_);
        }
    }
}